// Round 6
// baseline (303.569 us; speedup 1.0000x reference)
//
#include <hip/hip_runtime.h>
#include <math.h>

#define S_LEN 2048
#define HIDN  2048
#define NH    32
#define NKV   8
#define HD    64
#define KVW   (NKV * HD)     // 512
#define CTX   (S_LEN - 10)   // 2038: rows < CTX use boost rope, rows >= CTX use narrow

typedef unsigned short u16;
typedef __attribute__((ext_vector_type(4))) float f32x4;
typedef __attribute__((ext_vector_type(16))) float f32x16;
typedef __attribute__((ext_vector_type(8))) short s16x8;

#define QSCL 0.18033688011112042f    // 0.125 * log2(e): attn uses exp2(score)
#define L2_1E4 13.287712379549449f   // log2(10000)

__device__ __forceinline__ float bf2f(u16 u) {
  union { unsigned int i; float f; } v; v.i = ((unsigned int)u) << 16; return v.f;
}
__device__ __forceinline__ u16 f2bf(float f) {
  union { float f; unsigned int i; } v; v.f = f;
  unsigned int r = v.i + 0x7fffu + ((v.i >> 16) & 1u);
  return (u16)(r >> 16);
}
__device__ __forceinline__ unsigned int cvt_pk_bf16(float a, float b) {
  unsigned int d;
  asm("v_cvt_pk_bf16_f32 %0, %1, %2" : "=v"(d) : "v"(a), "v"(b));
  return d;
}

// ---------------------------------------------------------------------------
// fp32 -> bf16 conversion: hidden + Wq + Wk + Wv + Wo in one launch.
// ---------------------------------------------------------------------------
__global__ __launch_bounds__(256) void conv_all(
    const float* __restrict__ h,  const float* __restrict__ wq,
    const float* __restrict__ wk, const float* __restrict__ wv,
    const float* __restrict__ wo,
    u16* __restrict__ Hb, u16* __restrict__ Wqb, u16* __restrict__ Wkb,
    u16* __restrict__ Wvb, u16* __restrict__ Wob)
{
  const int i = blockIdx.x * 256 + threadIdx.x;   // one float4 per thread
  const float* src; u16* dst; int off;
  if      (i < 1048576) { src = h;  dst = Hb;  off = i; }
  else if (i < 2097152) { src = wq; dst = Wqb; off = i - 1048576; }
  else if (i < 2359296) { src = wk; dst = Wkb; off = i - 2097152; }
  else if (i < 2621440) { src = wv; dst = Wvb; off = i - 2359296; }
  else                  { src = wo; dst = Wob; off = i - 2621440; }
  const float4 f4 = ((const float4*)src)[off];
  ushort4 o4;
  o4.x = f2bf(f4.x); o4.y = f2bf(f4.y); o4.z = f2bf(f4.z); o4.w = f2bf(f4.w);
  ((ushort4*)dst)[off] = o4;
}

// ---------------------------------------------------------------------------
// GEMM: C[M,N] = A[M,K] * B[N,K]^T (bf16 in, fp32 accum), 128x64 tile, BK=64.
// Single-buffered m97-style loop (proven; dbuf/sched_barrier both measured
// regressions). 768/512 blocks -> 3/2 per CU, m114 implicit overlap.
// MODE: 0 = Q (fused rope boost/narrow + QSCL, bf16)
//       1 = K (fused rope dual: boost -> Cv, narrow -> Cv2, bf16)
//       2 = V (write C^T, row stride S_LEN, bf16)
//       3 = OUT (f32)
// ---------------------------------------------------------------------------
#define BM 128
#define BN 64
#define BK 64

template<int MODE>
__device__ __forceinline__ void gemm_body(
    u16* __restrict__ As, u16* __restrict__ Bs,
    const u16* __restrict__ A, const u16* __restrict__ B,
    void* __restrict__ Cv, void* __restrict__ Cv2,
    int N, int K, int row0, int col0, const int* __restrict__ pos)
{
  const int tid  = threadIdx.x;
  const int wave = tid >> 6;
  const int lane = tid & 63;
  const int l15  = lane & 15;
  const int wr   = wave * 32;          // wave's 32 output rows

  f32x4 acc[2][4] = {};

  const int srow = wave * 8 + (lane >> 3);   // 0..31
  const int scol = (lane & 7) * 8;

  for (int kt = 0; kt < K; kt += BK) {
#pragma unroll
    for (int it = 0; it < 4; ++it) {         // A: 128 rows
      const u16* gA = A + (size_t)(row0 + it * 32 + srow) * K + kt + scol;
      u16* lA = &As[(it * 32 + wave * 8) * BK];
      __builtin_amdgcn_global_load_lds((const __attribute__((address_space(1))) void*)gA,
                                       (__attribute__((address_space(3))) void*)lA, 16, 0, 0);
    }
#pragma unroll
    for (int it = 0; it < 2; ++it) {         // B: 64 rows
      const u16* gB = B + (size_t)(col0 + it * 32 + srow) * K + kt + scol;
      u16* lB = &Bs[(it * 32 + wave * 8) * BK];
      __builtin_amdgcn_global_load_lds((const __attribute__((address_space(1))) void*)gB,
                                       (__attribute__((address_space(3))) void*)lB, 16, 0, 0);
    }
    __syncthreads();                         // implicit vmcnt(0) drain + barrier
#pragma unroll
    for (int kk = 0; kk < 2; ++kk) {
      const int ko = kk * 32 + (lane >> 4) * 8;
      s16x8 af[2], bg[4];
#pragma unroll
      for (int mi = 0; mi < 2; ++mi)
        af[mi] = *(const s16x8*)&As[(wr + mi * 16 + l15) * BK + ko];
#pragma unroll
      for (int ni = 0; ni < 4; ++ni)
        bg[ni] = *(const s16x8*)&Bs[(ni * 16 + l15) * BK + ko];
#pragma unroll
      for (int mi = 0; mi < 2; ++mi)
#pragma unroll
        for (int ni = 0; ni < 4; ++ni)
          acc[mi][ni] = __builtin_amdgcn_mfma_f32_16x16x32_bf16(af[mi], bg[ni], acc[mi][ni], 0, 0, 0);
    }
    __syncthreads();
  }

  const int rq = (lane >> 4) * 4;
  const int cq = l15;

  if (MODE == 3) {
#pragma unroll
    for (int mi = 0; mi < 2; ++mi)
#pragma unroll
      for (int ni = 0; ni < 4; ++ni) {
        const int r = row0 + wr + mi * 16 + rq;
        const int c = col0 + ni * 16 + cq;
#pragma unroll
        for (int t = 0; t < 4; ++t)
          ((float*)Cv)[(size_t)(r + t) * N + c] = acc[mi][ni][t];
      }
  } else if (MODE == 2) {
#pragma unroll
    for (int mi = 0; mi < 2; ++mi)
#pragma unroll
      for (int ni = 0; ni < 4; ++ni) {
        const int r = row0 + wr + mi * 16 + rq;
        const int c = col0 + ni * 16 + cq;
        ushort4 o4;
        o4.x = f2bf(acc[mi][ni][0]); o4.y = f2bf(acc[mi][ni][1]);
        o4.z = f2bf(acc[mi][ni][2]); o4.w = f2bf(acc[mi][ni][3]);
        *(ushort4*)&((u16*)Cv)[(size_t)c * S_LEN + r] = o4;
      }
  } else {
    // MODE 0/1: fused rope. col0 is head-aligned (64): d = ni*16+cq (<32) pairs
    // with d+32 = cols of (mi, ni+2) -> rotate-half pair is thread-local.
    // Fast __sinf/__cosf: reduction err ~2e-4 rad at pos<=2047, << bf16 round.
#pragma unroll
    for (int mi = 0; mi < 2; ++mi) {
#pragma unroll
      for (int t = 0; t < 4; ++t) {
        const int i = row0 + wr + mi * 16 + rq + t;
        const float fpos = (float)pos[i];
#pragma unroll
        for (int ni = 0; ni < 2; ++ni) {
          const int d = ni * 16 + cq;            // 0..31
          const int c = col0 + d;
          const float f = exp2f(-(float)(2 * d) * (1.0f / HD) * L2_1E4);
          const float x1 = acc[mi][ni][t], x2 = acc[mi][ni + 2][t];
          if (MODE == 0) {
            const float scl = (i < CTX) ? 1.0f : 0.25f;
            const float a  = fpos * scl * f;
            const float cs = __cosf(a), sn = __sinf(a);
            u16* Cq = (u16*)Cv;
            Cq[(size_t)i * N + c]      = f2bf((x1 * cs - x2 * sn) * QSCL);
            Cq[(size_t)i * N + c + 32] = f2bf((x2 * cs + x1 * sn) * QSCL);
          } else {
            const float ab = fpos * f, an = fpos * 0.25f * f;
            const float cb_ = __cosf(ab), sb_ = __sinf(ab);
            const float cn_ = __cosf(an), sn_ = __sinf(an);
            ((u16*)Cv)[(size_t)i * N + c]       = f2bf(x1 * cb_ - x2 * sb_);
            ((u16*)Cv)[(size_t)i * N + c + 32]  = f2bf(x2 * cb_ + x1 * sb_);
            ((u16*)Cv2)[(size_t)i * N + c]      = f2bf(x1 * cn_ - x2 * sn_);
            ((u16*)Cv2)[(size_t)i * N + c + 32] = f2bf(x2 * cn_ + x1 * sn_);
          }
        }
      }
    }
  }
}

__global__ __launch_bounds__(256) void gemm_qkv(
    const u16* __restrict__ A, const u16* __restrict__ Wq, const u16* __restrict__ Wk,
    const u16* __restrict__ Wv, u16* __restrict__ Q, u16* __restrict__ Kb,
    u16* __restrict__ Kn, u16* __restrict__ Vt, const int* __restrict__ pos)
{
  __shared__ u16 As[BM * BK];
  __shared__ u16 Bs[BN * BK];
  const int bn = blockIdx.x;
  const int row0 = blockIdx.y * BM;
  if (bn < 32)
    gemm_body<0>(As, Bs, A, Wq, Q, nullptr, HIDN, HIDN, row0, bn * BN, pos);
  else if (bn < 40)
    gemm_body<1>(As, Bs, A, Wk, Kb, Kn, KVW, HIDN, row0, (bn - 32) * BN, pos);
  else
    gemm_body<2>(As, Bs, A, Wv, Vt, nullptr, KVW, HIDN, row0, (bn - 40) * BN, pos);
}

__global__ __launch_bounds__(256) void gemm_out(
    const u16* __restrict__ A, const u16* __restrict__ B, float* __restrict__ C, int N, int K)
{
  __shared__ u16 As[BM * BK];
  __shared__ u16 Bs[BN * BK];
  gemm_body<3>(As, Bs, A, B, C, nullptr, N, K, blockIdx.y * BM, blockIdx.x * BN, 0);
}

// ---------------------------------------------------------------------------
// MFMA flash attention, 32x32 swapped-QK^T, ZERO-LDS-staging / zero-barrier
// tile loop:
//  - grid 16 x NH; block p runs two 64-row q-tile phases {31-p, p}
//    (balanced: 33 key-tile iters per block).
//  - 4 waves split 2x2 over (row-half x key-half); swapped QK^T = mfma(K,Q),
//    lane owns one q-row, softmax lane-local; P->A-frag via cvt_pk+permlane.
//  - KEY CHANGE: the MFMA fragment layout IS the natural memory layout of
//    K (row-major) and Vt (dim-major), so each wave loads its fragments
//    DIRECTLY global->register (L1/L2-resident; K+V+Kn = 6MB), ping-pong
//    double-buffered one tile ahead via a 2-tile-unrolled loop (static reg
//    names, no dynamic indexing). No LDS staging, no staging-map VALU, no
//    barriers in the tile loop -- waves stream fully independently; a
//    wave's trip count nt_w excludes its fully-masked tiles.
//  - Kn fragments loaded just-in-time by the single CTX-straddle wave.
//  - LDS only for the per-phase cross-wave (O,lsum) merge (~17KB).
// ---------------------------------------------------------------------------
__global__ __launch_bounds__(256) void attn_mfma(
    const u16* __restrict__ Q, const u16* __restrict__ K, const u16* __restrict__ Kn,
    const u16* __restrict__ Vt, u16* __restrict__ O)
{
  __shared__ __align__(16) float Of[64][64];   // cross-wave O merge
  __shared__ float Lf[2][32];                  // cross-wave lsum merge
  __shared__ float Li[2][32];                  // per-row 1/l broadcast

  const int tid  = threadIdx.x;
  const int wave = tid >> 6;
  const int lane = tid & 63;
  const int l31  = lane & 31;
  const int hi   = lane >> 5;
  const int wr   = wave >> 1;                  // row half (0,1)
  const int wk   = wave & 1;                   // key half (0,1)
  const int h    = blockIdx.y;
  const int kh   = h >> 2;
  const int pr   = blockIdx.x;                 // pair index 0..15

  // wave-fragment base pointers (lane-resolved, natural layouts)
  const u16* Kp  = K  + (size_t)(wk * 32 + l31) * KVW + kh * HD;   // + t*64*KVW
  const u16* Knp = Kn + (size_t)(wk * 32 + l31) * KVW + kh * HD;
  const u16* Vp  = Vt + (size_t)(kh * HD + l31) * S_LEN;           // + t*64 + kc
  const u16* Vp2 = Vt + (size_t)(kh * HD + 32 + l31) * S_LEN;

  for (int ph = 0; ph < 2; ++ph) {
    const int qt = ph ? pr : 31 - pr;          // heavy tile first
    const int rw0 = qt * 64 + wr * 32;         // this wave's 32 q-rows
    const bool mixed_wv = (qt == 31) && (rw0 + 31 >= CTX);

    // persistent Q B-frags: B[n=q=l31][k=d = i*16 + hi*8 + j]
    s16x8 bq[4];
#pragma unroll
    for (int i = 0; i < 4; ++i)
      bq[i] = *(const s16x8*)(Q + (size_t)(rw0 + l31) * HIDN + h * HD + i * 16 + hi * 8);

    f32x16 acc0 = {};      // O[q][d], d = l31       (rows in reg pattern)
    f32x16 acc1 = {};      // O[q][d], d = l31 + 32
    float lsum = 0.f;      // partial row sum (this lane's 16 keys)

    // per-wave trip count: tiles whose key group j0 = t*64+wk*32 has
    // j0 <= rw0+31 (anything beyond is fully masked for this wave)
    const int m    = rw0 + 31 - wk * 32;
    const int nt_w = (m < 0) ? 0 : (m >> 6) + 1;

    auto LK = [&](s16x8* d, int tt) {
      const u16* p = Kp + (size_t)(tt * 64) * KVW;
#pragma unroll
      for (int i = 0; i < 4; ++i) d[i] = *(const s16x8*)(p + i * 16 + hi * 8);
    };
    auto LV = [&](s16x8* d, int tt) {
      const int c0 = tt * 64 + wk * 32 + hi * 8;
      d[0] = *(const s16x8*)(Vp  + c0);
      d[1] = *(const s16x8*)(Vp2 + c0);
      d[2] = *(const s16x8*)(Vp  + c0 + 16);
      d[3] = *(const s16x8*)(Vp2 + c0 + 16);
    };

    auto COMPUTE = [&](const s16x8* kf, const s16x8* vf, int t) {
      const int j0 = t * 64 + wk * 32;         // this wave's 32-key group
      const bool needmask = (j0 + 31 > rw0);   // straddles the diagonal

      // swapped QK^T: D[m=key (reg pattern)][n=q (l31)]
      f32x16 sc = {};
#pragma unroll
      for (int i = 0; i < 4; ++i)
        sc = __builtin_amdgcn_mfma_f32_32x32x16_bf16(kf[i], bq[i], sc, 0, 0, 0);
      if (mixed_wv) {                          // rows straddle CTX: also narrow
        const u16* p = Knp + (size_t)(t * 64) * KVW;
        f32x16 scn = {};
#pragma unroll
        for (int i = 0; i < 4; ++i) {
          const s16x8 ak = *(const s16x8*)(p + i * 16 + hi * 8);
          scn = __builtin_amdgcn_mfma_f32_32x32x16_bf16(ak, bq[i], scn, 0, 0, 0);
        }
        const bool nar = (rw0 + l31) >= CTX;   // per-lane: q-row selects rope
#pragma unroll
        for (int r = 0; r < 16; ++r) sc[r] = nar ? scn[r] : sc[r];
      }

      // lane-local softmax: p = exp2(min(s,80)) (Q pre-scaled by log2e/8)
      float p[16];
#pragma unroll
      for (int r = 0; r < 16; ++r) {
        float e = __builtin_amdgcn_exp2f(fminf(sc[r], 80.f));
        if (needmask) {
          const int key = j0 + (r & 3) + 8 * (r >> 2) + 4 * hi;
          e = (key > rw0 + l31) ? 0.f : e;
        }
        p[r] = e;
        lsum += e;
      }

      // pack p -> bf16 pairs: c[blk][j] = keys 8*blk + 4*hi + {2j, 2j+1}
      unsigned int c[4][2];
#pragma unroll
      for (int blk = 0; blk < 4; ++blk) {
        c[blk][0] = cvt_pk_bf16(p[4 * blk + 0], p[4 * blk + 1]);
        c[blk][1] = cvt_pk_bf16(p[4 * blk + 2], p[4 * blk + 3]);
      }

      // per 16-key slice s: swap halves -> A-frag words, then 2 PV MFMAs
#pragma unroll
      for (int s = 0; s < 2; ++s) {
        unsigned int w0 = c[2 * s][0], w2 = c[2 * s + 1][0];
        unsigned int w1 = c[2 * s][1], w3 = c[2 * s + 1][1];
        asm("v_permlane32_swap_b32 %0, %1" : "+v"(w0), "+v"(w2));
        asm("v_permlane32_swap_b32 %0, %1" : "+v"(w1), "+v"(w3));
        union { unsigned int u[4]; s16x8 v; } af;
        af.u[0] = w0; af.u[1] = w1; af.u[2] = w2; af.u[3] = w3;
        acc0 = __builtin_amdgcn_mfma_f32_32x32x16_bf16(af.v, vf[2 * s],     acc0, 0, 0, 0);
        acc1 = __builtin_amdgcn_mfma_f32_32x32x16_bf16(af.v, vf[2 * s + 1], acc1, 0, 0, 0);
      }
    };

    // 2-tile-unrolled ping-pong: loads for the next tile issue before the
    // current tile's compute (register dbuf, static names, no barriers)
    s16x8 ka[4], va[4], kb[4], vb[4];
    int t = 0;
    if (nt_w > 0) {
      LK(ka, 0); LV(va, 0);
      for (; t + 1 < nt_w; t += 2) {
        LK(kb, t + 1); LV(vb, t + 1);
        COMPUTE(ka, va, t);
        if (t + 2 < nt_w) { LK(ka, t + 2); LV(va, t + 2); }
        COMPUTE(kb, vb, t + 1);
      }
      if (t < nt_w) COMPUTE(ka, va, t);        // odd tail (already loaded)
    }

    // ---- cross-wave merge over key halves + epilogue (per phase) ----
    lsum += __shfl_xor(lsum, 32, 64);         // combine hi halves: row sum over
                                              // this wave's 32 keys, row = rw0+l31
    if (wk == 1) {
#pragma unroll
      for (int r = 0; r < 16; ++r) {
        const int rl = (r & 3) + 8 * (r >> 2) + 4 * hi;
        Of[wr * 32 + rl][l31]      = acc0[r];
        Of[wr * 32 + rl][l31 + 32] = acc1[r];
      }
      if (hi == 0) Lf[wr][l31] = lsum;
    }
    __syncthreads();
    if (wk == 0) {
      const float tot = lsum + Lf[wr][l31];
      const float inv = 1.0f / fmaxf(tot, 1e-30f);
      if (hi == 0) Li[wr][l31] = inv;         // same-wave write->read (in-order LDS)
#pragma unroll
      for (int r = 0; r < 16; ++r) {
        const int rl = (r & 3) + 8 * (r >> 2) + 4 * hi;
        const float iv = Li[wr][rl];
        const size_t o = (size_t)(rw0 + rl) * HIDN + h * HD + l31;
        O[o]      = f2bf((acc0[r] + Of[wr * 32 + rl][l31])      * iv);
        O[o + 32] = f2bf((acc1[r] + Of[wr * 32 + rl][l31 + 32]) * iv);
      }
    }
    __syncthreads();     // Of/Lf free before next phase reuses them
  }
}

// ---------------------------------------------------------------------------
extern "C" void kernel_launch(void* const* d_in, const int* in_sizes, int n_in,
                              void* d_out, int out_size, void* d_ws, size_t ws_size,
                              hipStream_t stream)
{
  const float* hidden = (const float*)d_in[0];
  const int* pos      = (const int*)d_in[2];   // d_in[1] mask: pure causal, unused
  const float* Wq = (const float*)d_in[3];
  const float* Wk = (const float*)d_in[4];
  const float* Wv = (const float*)d_in[5];
  const float* Wo = (const float*)d_in[6];
  float* out = (float*)d_out;

  char* ws = (char*)d_ws;
  u16* Qb  = (u16*)(ws);                    // 8 MB  bf16 Q (roped+scaled by gemm)
  u16* Kbb = (u16*)(ws + (8u  << 20));      // 2 MB  bf16 boost K (roped by gemm)
  u16* Knb = (u16*)(ws + (10u << 20));      // 2 MB  bf16 narrow K
  u16* Vtb = (u16*)(ws + (12u << 20));      // 2 MB  bf16 V transposed [kv_col][seq]
  u16* Ab  = (u16*)(ws + (14u << 20));      // 8 MB  bf16 attention output
  u16* Hb  = (u16*)(ws + (22u << 20));      // 8 MB  bf16 hidden
  u16* Wqb = (u16*)(ws + (30u << 20));      // 8 MB  bf16 Wq
  u16* Wkb = (u16*)(ws + (38u << 20));      // 2 MB  bf16 Wk
  u16* Wvb = (u16*)(ws + (40u << 20));      // 2 MB  bf16 Wv
  u16* Wob = (u16*)(ws + (42u << 20));      // 8 MB  bf16 Wo  => 50 MB total

  conv_all<<<dim3(14336), 256, 0, stream>>>(hidden, Wq, Wk, Wv, Wo, Hb, Wqb, Wkb, Wvb, Wob);
  gemm_qkv<<<dim3(48, 16), 256, 0, stream>>>(Hb, Wqb, Wkb, Wvb, Qb, Kbb, Knb, Vtb, pos);
  attn_mfma<<<dim3(16, NH), 256, 0, stream>>>(Qb, Kbb, Knb, Vtb, Ab);
  gemm_out<<<dim3(32, 16), 256, 0, stream>>>(Ab, Wob, out, HIDN, HIDN);
}

// Round 7
// 301.198 us; speedup vs baseline: 1.0079x; 1.0079x over previous
//
#include <hip/hip_runtime.h>
#include <math.h>

#define S_LEN 2048
#define HIDN  2048
#define NH    32
#define NKV   8
#define HD    64
#define KVW   (NKV * HD)     // 512
#define CTX   (S_LEN - 10)   // 2038: rows < CTX use boost rope, rows >= CTX use narrow

typedef unsigned short u16;
typedef __attribute__((ext_vector_type(4))) float f32x4;
typedef __attribute__((ext_vector_type(16))) float f32x16;
typedef __attribute__((ext_vector_type(8))) short s16x8;

#define QSCL 0.18033688011112042f    // 0.125 * log2(e): attn uses exp2(score)
#define L2_1E4 13.287712379549449f   // log2(10000)

__device__ __forceinline__ float bf2f(u16 u) {
  union { unsigned int i; float f; } v; v.i = ((unsigned int)u) << 16; return v.f;
}
__device__ __forceinline__ u16 f2bf(float f) {
  union { float f; unsigned int i; } v; v.f = f;
  unsigned int r = v.i + 0x7fffu + ((v.i >> 16) & 1u);
  return (u16)(r >> 16);
}
__device__ __forceinline__ unsigned int cvt_pk_bf16(float a, float b) {
  unsigned int d;
  asm("v_cvt_pk_bf16_f32 %0, %1, %2" : "=v"(d) : "v"(a), "v"(b));
  return d;
}

// ---------------------------------------------------------------------------
// fp32 -> bf16 conversion: hidden + Wq + Wk + Wv + Wo in one launch.
// ---------------------------------------------------------------------------
__global__ __launch_bounds__(256) void conv_all(
    const float* __restrict__ h,  const float* __restrict__ wq,
    const float* __restrict__ wk, const float* __restrict__ wv,
    const float* __restrict__ wo,
    u16* __restrict__ Hb, u16* __restrict__ Wqb, u16* __restrict__ Wkb,
    u16* __restrict__ Wvb, u16* __restrict__ Wob)
{
  const int i = blockIdx.x * 256 + threadIdx.x;   // one float4 per thread
  const float* src; u16* dst; int off;
  if      (i < 1048576) { src = h;  dst = Hb;  off = i; }
  else if (i < 2097152) { src = wq; dst = Wqb; off = i - 1048576; }
  else if (i < 2359296) { src = wk; dst = Wkb; off = i - 2097152; }
  else if (i < 2621440) { src = wv; dst = Wvb; off = i - 2359296; }
  else                  { src = wo; dst = Wob; off = i - 2621440; }
  const float4 f4 = ((const float4*)src)[off];
  ushort4 o4;
  o4.x = f2bf(f4.x); o4.y = f2bf(f4.y); o4.z = f2bf(f4.z); o4.w = f2bf(f4.w);
  ((ushort4*)dst)[off] = o4;
}

// ---------------------------------------------------------------------------
// GEMM: C[M,N] = A[M,K] * B[N,K]^T (bf16 in, fp32 accum), 128x64 tile, BK=64.
// Single-buffered m97-style loop (proven; dbuf/sched_barrier both measured
// regressions). 768/512 blocks -> 3/2 per CU, m114 implicit overlap.
// MODE: 0 = Q (fused rope boost/narrow + QSCL, bf16)
//       1 = K (fused rope dual: boost -> Cv, narrow -> Cv2, bf16)
//       2 = V (write C^T, row stride S_LEN, bf16)
//       3 = OUT (f32)
// ---------------------------------------------------------------------------
#define BM 128
#define BN 64
#define BK 64

template<int MODE>
__device__ __forceinline__ void gemm_body(
    u16* __restrict__ As, u16* __restrict__ Bs,
    const u16* __restrict__ A, const u16* __restrict__ B,
    void* __restrict__ Cv, void* __restrict__ Cv2,
    int N, int K, int row0, int col0, const int* __restrict__ pos)
{
  const int tid  = threadIdx.x;
  const int wave = tid >> 6;
  const int lane = tid & 63;
  const int l15  = lane & 15;
  const int wr   = wave * 32;          // wave's 32 output rows

  f32x4 acc[2][4] = {};

  const int srow = wave * 8 + (lane >> 3);   // 0..31
  const int scol = (lane & 7) * 8;

  for (int kt = 0; kt < K; kt += BK) {
#pragma unroll
    for (int it = 0; it < 4; ++it) {         // A: 128 rows
      const u16* gA = A + (size_t)(row0 + it * 32 + srow) * K + kt + scol;
      u16* lA = &As[(it * 32 + wave * 8) * BK];
      __builtin_amdgcn_global_load_lds((const __attribute__((address_space(1))) void*)gA,
                                       (__attribute__((address_space(3))) void*)lA, 16, 0, 0);
    }
#pragma unroll
    for (int it = 0; it < 2; ++it) {         // B: 64 rows
      const u16* gB = B + (size_t)(col0 + it * 32 + srow) * K + kt + scol;
      u16* lB = &Bs[(it * 32 + wave * 8) * BK];
      __builtin_amdgcn_global_load_lds((const __attribute__((address_space(1))) void*)gB,
                                       (__attribute__((address_space(3))) void*)lB, 16, 0, 0);
    }
    __syncthreads();                         // implicit vmcnt(0) drain + barrier
#pragma unroll
    for (int kk = 0; kk < 2; ++kk) {
      const int ko = kk * 32 + (lane >> 4) * 8;
      s16x8 af[2], bg[4];
#pragma unroll
      for (int mi = 0; mi < 2; ++mi)
        af[mi] = *(const s16x8*)&As[(wr + mi * 16 + l15) * BK + ko];
#pragma unroll
      for (int ni = 0; ni < 4; ++ni)
        bg[ni] = *(const s16x8*)&Bs[(ni * 16 + l15) * BK + ko];
#pragma unroll
      for (int mi = 0; mi < 2; ++mi)
#pragma unroll
        for (int ni = 0; ni < 4; ++ni)
          acc[mi][ni] = __builtin_amdgcn_mfma_f32_16x16x32_bf16(af[mi], bg[ni], acc[mi][ni], 0, 0, 0);
    }
    __syncthreads();
  }

  const int rq = (lane >> 4) * 4;
  const int cq = l15;

  if (MODE == 3) {
#pragma unroll
    for (int mi = 0; mi < 2; ++mi)
#pragma unroll
      for (int ni = 0; ni < 4; ++ni) {
        const int r = row0 + wr + mi * 16 + rq;
        const int c = col0 + ni * 16 + cq;
#pragma unroll
        for (int t = 0; t < 4; ++t)
          ((float*)Cv)[(size_t)(r + t) * N + c] = acc[mi][ni][t];
      }
  } else if (MODE == 2) {
#pragma unroll
    for (int mi = 0; mi < 2; ++mi)
#pragma unroll
      for (int ni = 0; ni < 4; ++ni) {
        const int r = row0 + wr + mi * 16 + rq;
        const int c = col0 + ni * 16 + cq;
        ushort4 o4;
        o4.x = f2bf(acc[mi][ni][0]); o4.y = f2bf(acc[mi][ni][1]);
        o4.z = f2bf(acc[mi][ni][2]); o4.w = f2bf(acc[mi][ni][3]);
        *(ushort4*)&((u16*)Cv)[(size_t)c * S_LEN + r] = o4;
      }
  } else {
    // MODE 0/1: fused rope. col0 is head-aligned (64): d = ni*16+cq (<32) pairs
    // with d+32 = cols of (mi, ni+2) -> rotate-half pair is thread-local.
    // Fast __sinf/__cosf: reduction err ~2e-4 rad at pos<=2047, << bf16 round.
#pragma unroll
    for (int mi = 0; mi < 2; ++mi) {
#pragma unroll
      for (int t = 0; t < 4; ++t) {
        const int i = row0 + wr + mi * 16 + rq + t;
        const float fpos = (float)pos[i];
#pragma unroll
        for (int ni = 0; ni < 2; ++ni) {
          const int d = ni * 16 + cq;            // 0..31
          const int c = col0 + d;
          const float f = exp2f(-(float)(2 * d) * (1.0f / HD) * L2_1E4);
          const float x1 = acc[mi][ni][t], x2 = acc[mi][ni + 2][t];
          if (MODE == 0) {
            const float scl = (i < CTX) ? 1.0f : 0.25f;
            const float a  = fpos * scl * f;
            const float cs = __cosf(a), sn = __sinf(a);
            u16* Cq = (u16*)Cv;
            Cq[(size_t)i * N + c]      = f2bf((x1 * cs - x2 * sn) * QSCL);
            Cq[(size_t)i * N + c + 32] = f2bf((x2 * cs + x1 * sn) * QSCL);
          } else {
            const float ab = fpos * f, an = fpos * 0.25f * f;
            const float cb_ = __cosf(ab), sb_ = __sinf(ab);
            const float cn_ = __cosf(an), sn_ = __sinf(an);
            ((u16*)Cv)[(size_t)i * N + c]       = f2bf(x1 * cb_ - x2 * sb_);
            ((u16*)Cv)[(size_t)i * N + c + 32]  = f2bf(x2 * cb_ + x1 * sb_);
            ((u16*)Cv2)[(size_t)i * N + c]      = f2bf(x1 * cn_ - x2 * sn_);
            ((u16*)Cv2)[(size_t)i * N + c + 32] = f2bf(x2 * cn_ + x1 * sn_);
          }
        }
      }
    }
  }
}

__global__ __launch_bounds__(256) void gemm_qkv(
    const u16* __restrict__ A, const u16* __restrict__ Wq, const u16* __restrict__ Wk,
    const u16* __restrict__ Wv, u16* __restrict__ Q, u16* __restrict__ Kb,
    u16* __restrict__ Kn, u16* __restrict__ Vt, const int* __restrict__ pos)
{
  __shared__ u16 As[BM * BK];
  __shared__ u16 Bs[BN * BK];
  const int bn = blockIdx.x;
  const int row0 = blockIdx.y * BM;
  if (bn < 32)
    gemm_body<0>(As, Bs, A, Wq, Q, nullptr, HIDN, HIDN, row0, bn * BN, pos);
  else if (bn < 40)
    gemm_body<1>(As, Bs, A, Wk, Kb, Kn, KVW, HIDN, row0, (bn - 32) * BN, pos);
  else
    gemm_body<2>(As, Bs, A, Wv, Vt, nullptr, KVW, HIDN, row0, (bn - 40) * BN, pos);
}

__global__ __launch_bounds__(256) void gemm_out(
    const u16* __restrict__ A, const u16* __restrict__ B, float* __restrict__ C, int N, int K)
{
  __shared__ u16 As[BM * BK];
  __shared__ u16 Bs[BN * BK];
  gemm_body<3>(As, Bs, A, B, C, nullptr, N, K, blockIdx.y * BM, blockIdx.x * BN, 0);
}

// ---------------------------------------------------------------------------
// MFMA flash attention, 32x32 swapped-QK^T, 4-blocks/CU occupancy build:
//  - grid 32 x NH: ONE 64-row q-tile per block (no triangle pairing), heavy
//    tiles dispatched first (qt = 31 - bx); dynamic HW backfill balances the
//    qt+1-proportional work at 4-deep residency (1024 blocks = 4/CU, 16
//    waves/CU = 4/SIMD -- double round-5's TLP, which was the latency limit).
//  - 4 waves split 2x2 over (row-half x key-half); swapped QK^T = mfma(K,Q),
//    lane owns one q-row, softmax lane-local; P->A-frag via cvt_pk+permlane
//    (all machinery proven in rounds 2-5, bank-conflict-free).
//  - Kns LDS staging dropped (would cost the 4th block/CU): the single
//    CTX-straddle wave (qt==31, wr==1) gather-loads its Kn fragments
//    directly from global, issued ahead of the QK^T MFMAs to hide latency.
//  - LDS 36KB: Ks + Vts + Of merge buffers; 2-barrier r2 loop + 1-tile
//    register prefetch of the next K/V tile.
// ---------------------------------------------------------------------------
#define PAD 8
__global__ __launch_bounds__(256, 4) void attn_mfma(
    const u16* __restrict__ Q, const u16* __restrict__ K, const u16* __restrict__ Kn,
    const u16* __restrict__ Vt, u16* __restrict__ O)
{
  __shared__ __align__(16) u16 Ks[64][HD + PAD];
  __shared__ __align__(16) u16 Vts[HD][64 + PAD];
  __shared__ __align__(16) float Of[64][64];   // cross-wave O merge
  __shared__ float Lf[2][32];                  // cross-wave lsum merge
  __shared__ float Li[2][32];                  // per-row 1/l broadcast

  const int tid  = threadIdx.x;
  const int wave = tid >> 6;
  const int lane = tid & 63;
  const int l31  = lane & 31;
  const int hi   = lane >> 5;
  const int wr   = wave >> 1;                  // row half (0,1)
  const int wk   = wave & 1;                   // key half (0,1)
  const int h    = blockIdx.y;
  const int kh   = h >> 2;
  const int qt   = 31 - (int)blockIdx.x;       // heavy q-tiles dispatch first
  const int rw0  = qt * 64 + wr * 32;          // this wave's 32 q-rows
  const bool mixed_wv = (qt == 31) && (rw0 + 31 >= CTX);

  // staging map: 2 iters x 256 threads x 16B cover one 64x64 bf16 tile
  int sa[2], sb[2];
#pragma unroll
  for (int it = 0; it < 2; ++it) {
    const int u = it * 256 + tid;
    sa[it] = u >> 3;
    sb[it] = (u & 7) * 8;
  }

  // persistent Q B-frags: B[n=q=l31][k=d = i*16 + hi*8 + j]
  s16x8 bq[4];
#pragma unroll
  for (int i = 0; i < 4; ++i)
    bq[i] = *(const s16x8*)(Q + (size_t)(rw0 + l31) * HIDN + h * HD + i * 16 + hi * 8);

  f32x16 acc0 = {};      // O[q][d], d = l31       (rows in reg pattern)
  f32x16 acc1 = {};      // O[q][d], d = l31 + 32
  float lsum = 0.f;      // partial row sum (this lane's 16 keys)

  const int ntiles = qt + 1;
  s16x8 kr[2], vr[2];
#pragma unroll
  for (int it = 0; it < 2; ++it) {
    kr[it] = *(const s16x8*)(K  + (size_t)sa[it] * KVW + kh * HD + sb[it]);
    vr[it] = *(const s16x8*)(Vt + (size_t)(kh * HD + sa[it]) * S_LEN + sb[it]);
  }

  // lane-resolved Kn fragment base for the straddle wave (gather path)
  const u16* Knp = Kn + (size_t)(wk * 32 + l31) * KVW + kh * HD;

  for (int t = 0; t < ntiles; ++t) {
    const int jt = t * 64;
    __syncthreads();                        // LDS free (prev tile's reads done)
#pragma unroll
    for (int it = 0; it < 2; ++it) {
      *(s16x8*)&Ks[sa[it]][sb[it]]  = kr[it];
      *(s16x8*)&Vts[sa[it]][sb[it]] = vr[it];
    }
    __syncthreads();                        // LDS ready
    if (t + 1 < ntiles) {                   // prefetch next tile (overlaps compute)
      const int jn = jt + 64;
#pragma unroll
      for (int it = 0; it < 2; ++it) {
        kr[it] = *(const s16x8*)(K  + (size_t)(jn + sa[it]) * KVW + kh * HD + sb[it]);
        vr[it] = *(const s16x8*)(Vt + (size_t)(kh * HD + sa[it]) * S_LEN + jn + sb[it]);
      }
    }

    const int j0 = jt + wk * 32;            // this wave's 32-key group
    if (j0 > rw0 + 31) continue;            // fully masked for this wave
    const bool needmask = (j0 + 31 > rw0);  // straddles the diagonal

    // straddle wave: issue Kn gather loads early (overlap with QK^T MFMAs)
    s16x8 akn[4];
    if (mixed_wv) {
      const u16* p = Knp + (size_t)jt * KVW;
#pragma unroll
      for (int i = 0; i < 4; ++i) akn[i] = *(const s16x8*)(p + i * 16 + hi * 8);
    }

    // swapped QK^T: D[m=key (reg pattern)][n=q (l31)]
    f32x16 sc = {};
#pragma unroll
    for (int i = 0; i < 4; ++i) {
      const s16x8 ak = *(const s16x8*)&Ks[wk * 32 + l31][i * 16 + hi * 8];
      sc = __builtin_amdgcn_mfma_f32_32x32x16_bf16(ak, bq[i], sc, 0, 0, 0);
    }
    if (mixed_wv) {                         // rows straddle CTX: also narrow
      f32x16 scn = {};
#pragma unroll
      for (int i = 0; i < 4; ++i)
        scn = __builtin_amdgcn_mfma_f32_32x32x16_bf16(akn[i], bq[i], scn, 0, 0, 0);
      const bool nar = (rw0 + l31) >= CTX;  // per-lane: q-row selects rope
#pragma unroll
      for (int r = 0; r < 16; ++r) sc[r] = nar ? scn[r] : sc[r];
    }

    // lane-local softmax: p = exp2(min(s,80)) (Q pre-scaled by log2e/8)
    float p[16];
#pragma unroll
    for (int r = 0; r < 16; ++r) {
      float e = __builtin_amdgcn_exp2f(fminf(sc[r], 80.f));
      if (needmask) {
        const int key = j0 + (r & 3) + 8 * (r >> 2) + 4 * hi;
        e = (key > rw0 + l31) ? 0.f : e;
      }
      p[r] = e;
      lsum += e;
    }

    // pack p -> bf16 pairs: c[blk][j] = keys 8*blk + 4*hi + {2j, 2j+1}
    unsigned int c[4][2];
#pragma unroll
    for (int blk = 0; blk < 4; ++blk) {
      c[blk][0] = cvt_pk_bf16(p[4 * blk + 0], p[4 * blk + 1]);
      c[blk][1] = cvt_pk_bf16(p[4 * blk + 2], p[4 * blk + 3]);
    }

    // per 16-key slice s: swap halves -> A-frag words, then 2 PV MFMAs
#pragma unroll
    for (int s = 0; s < 2; ++s) {
      unsigned int w0 = c[2 * s][0], w2 = c[2 * s + 1][0];
      unsigned int w1 = c[2 * s][1], w3 = c[2 * s + 1][1];
      asm("v_permlane32_swap_b32 %0, %1" : "+v"(w0), "+v"(w2));
      asm("v_permlane32_swap_b32 %0, %1" : "+v"(w1), "+v"(w3));
      union { unsigned int u[4]; s16x8 v; } af;
      af.u[0] = w0; af.u[1] = w1; af.u[2] = w2; af.u[3] = w3;
      const int kc = wk * 32 + s * 16 + hi * 8;
      const s16x8 v0 = *(const s16x8*)&Vts[l31][kc];
      const s16x8 v1 = *(const s16x8*)&Vts[32 + l31][kc];
      acc0 = __builtin_amdgcn_mfma_f32_32x32x16_bf16(af.v, v0, acc0, 0, 0, 0);
      acc1 = __builtin_amdgcn_mfma_f32_32x32x16_bf16(af.v, v1, acc1, 0, 0, 0);
    }
  }

  // ---- cross-wave merge over key halves + epilogue ----
  lsum += __shfl_xor(lsum, 32, 64);         // combine hi halves: row sum over
                                            // this wave's 32 keys, row = rw0+l31
  __syncthreads();                          // all compute done; LDS tiles free
  if (wk == 1) {
#pragma unroll
    for (int r = 0; r < 16; ++r) {
      const int rl = (r & 3) + 8 * (r >> 2) + 4 * hi;
      Of[wr * 32 + rl][l31]      = acc0[r];
      Of[wr * 32 + rl][l31 + 32] = acc1[r];
    }
    if (hi == 0) Lf[wr][l31] = lsum;
  }
  __syncthreads();
  if (wk == 0) {
    const float tot = lsum + Lf[wr][l31];
    const float inv = 1.0f / fmaxf(tot, 1e-30f);
    if (hi == 0) Li[wr][l31] = inv;         // same-wave write->read (in-order LDS)
#pragma unroll
    for (int r = 0; r < 16; ++r) {
      const int rl = (r & 3) + 8 * (r >> 2) + 4 * hi;
      const float iv = Li[wr][rl];
      const size_t o = (size_t)(rw0 + rl) * HIDN + h * HD + l31;
      O[o]      = f2bf((acc0[r] + Of[wr * 32 + rl][l31])      * iv);
      O[o + 32] = f2bf((acc1[r] + Of[wr * 32 + rl][l31 + 32]) * iv);
    }
  }
}

// ---------------------------------------------------------------------------
extern "C" void kernel_launch(void* const* d_in, const int* in_sizes, int n_in,
                              void* d_out, int out_size, void* d_ws, size_t ws_size,
                              hipStream_t stream)
{
  const float* hidden = (const float*)d_in[0];
  const int* pos      = (const int*)d_in[2];   // d_in[1] mask: pure causal, unused
  const float* Wq = (const float*)d_in[3];
  const float* Wk = (const float*)d_in[4];
  const float* Wv = (const float*)d_in[5];
  const float* Wo = (const float*)d_in[6];
  float* out = (float*)d_out;

  char* ws = (char*)d_ws;
  u16* Qb  = (u16*)(ws);                    // 8 MB  bf16 Q (roped+scaled by gemm)
  u16* Kbb = (u16*)(ws + (8u  << 20));      // 2 MB  bf16 boost K (roped by gemm)
  u16* Knb = (u16*)(ws + (10u << 20));      // 2 MB  bf16 narrow K
  u16* Vtb = (u16*)(ws + (12u << 20));      // 2 MB  bf16 V transposed [kv_col][seq]
  u16* Ab  = (u16*)(ws + (14u << 20));      // 8 MB  bf16 attention output
  u16* Hb  = (u16*)(ws + (22u << 20));      // 8 MB  bf16 hidden
  u16* Wqb = (u16*)(ws + (30u << 20));      // 8 MB  bf16 Wq
  u16* Wkb = (u16*)(ws + (38u << 20));      // 2 MB  bf16 Wk
  u16* Wvb = (u16*)(ws + (40u << 20));      // 2 MB  bf16 Wv
  u16* Wob = (u16*)(ws + (42u << 20));      // 8 MB  bf16 Wo  => 50 MB total

  conv_all<<<dim3(14336), 256, 0, stream>>>(hidden, Wq, Wk, Wv, Wo, Hb, Wqb, Wkb, Wvb, Wob);
  gemm_qkv<<<dim3(48, 16), 256, 0, stream>>>(Hb, Wqb, Wkb, Wvb, Qb, Kbb, Knb, Vtb, pos);
  attn_mfma<<<dim3(32, NH), 256, 0, stream>>>(Qb, Kbb, Knb, Vtb, Ab);
  gemm_out<<<dim3(32, 16), 256, 0, stream>>>(Ab, Wob, out, HIDN, HIDN);
}

// Round 8
// 297.039 us; speedup vs baseline: 1.0220x; 1.0140x over previous
//
#include <hip/hip_runtime.h>
#include <math.h>

#define S_LEN 2048
#define HIDN  2048
#define NH    32
#define NKV   8
#define HD    64
#define KVW   (NKV * HD)     // 512
#define CTX   (S_LEN - 10)   // 2038: rows < CTX use boost rope, rows >= CTX use narrow

typedef unsigned short u16;
typedef __attribute__((ext_vector_type(4))) float f32x4;
typedef __attribute__((ext_vector_type(16))) float f32x16;
typedef __attribute__((ext_vector_type(8))) short s16x8;

#define QSCL 0.18033688011112042f    // 0.125 * log2(e): attn uses exp2(score)
#define L2_1E4 13.287712379549449f   // log2(10000)

__device__ __forceinline__ float bf2f(u16 u) {
  union { unsigned int i; float f; } v; v.i = ((unsigned int)u) << 16; return v.f;
}
__device__ __forceinline__ u16 f2bf(float f) {
  union { float f; unsigned int i; } v; v.f = f;
  unsigned int r = v.i + 0x7fffu + ((v.i >> 16) & 1u);
  return (u16)(r >> 16);
}
__device__ __forceinline__ unsigned int cvt_pk_bf16(float a, float b) {
  unsigned int d;
  asm("v_cvt_pk_bf16_f32 %0, %1, %2" : "=v"(d) : "v"(a), "v"(b));
  return d;
}

// ---------------------------------------------------------------------------
// fp32 -> bf16 conversion: hidden + Wq + Wk + Wv + Wo in one launch.
// ---------------------------------------------------------------------------
__global__ __launch_bounds__(256) void conv_all(
    const float* __restrict__ h,  const float* __restrict__ wq,
    const float* __restrict__ wk, const float* __restrict__ wv,
    const float* __restrict__ wo,
    u16* __restrict__ Hb, u16* __restrict__ Wqb, u16* __restrict__ Wkb,
    u16* __restrict__ Wvb, u16* __restrict__ Wob)
{
  const int i = blockIdx.x * 256 + threadIdx.x;   // one float4 per thread
  const float* src; u16* dst; int off;
  if      (i < 1048576) { src = h;  dst = Hb;  off = i; }
  else if (i < 2097152) { src = wq; dst = Wqb; off = i - 1048576; }
  else if (i < 2359296) { src = wk; dst = Wkb; off = i - 2097152; }
  else if (i < 2621440) { src = wv; dst = Wvb; off = i - 2359296; }
  else                  { src = wo; dst = Wob; off = i - 2621440; }
  const float4 f4 = ((const float4*)src)[off];
  ushort4 o4;
  o4.x = f2bf(f4.x); o4.y = f2bf(f4.y); o4.z = f2bf(f4.z); o4.w = f2bf(f4.w);
  ((ushort4*)dst)[off] = o4;
}

// ---------------------------------------------------------------------------
// GEMM: C[M,N] = A[M,K] * B[N,K]^T (bf16 in, fp32 accum), 128x64 tile, BK=64.
// Single-buffered m97-style loop (proven; dbuf/sched_barrier both measured
// regressions). 768/512 blocks -> 3/2 per CU, m114 implicit overlap.
// MODE: 0 = Q (fused rope boost/narrow + QSCL, bf16)
//       1 = K (fused rope dual: boost -> Cv, narrow -> Cv2, bf16)
//       2 = V (write C^T, row stride S_LEN, bf16)
//       3 = OUT (f32)
// ---------------------------------------------------------------------------
#define BM 128
#define BN 64
#define BK 64

template<int MODE>
__device__ __forceinline__ void gemm_body(
    u16* __restrict__ As, u16* __restrict__ Bs,
    const u16* __restrict__ A, const u16* __restrict__ B,
    void* __restrict__ Cv, void* __restrict__ Cv2,
    int N, int K, int row0, int col0, const int* __restrict__ pos)
{
  const int tid  = threadIdx.x;
  const int wave = tid >> 6;
  const int lane = tid & 63;
  const int l15  = lane & 15;
  const int wr   = wave * 32;          // wave's 32 output rows

  f32x4 acc[2][4] = {};

  const int srow = wave * 8 + (lane >> 3);   // 0..31
  const int scol = (lane & 7) * 8;

  for (int kt = 0; kt < K; kt += BK) {
#pragma unroll
    for (int it = 0; it < 4; ++it) {         // A: 128 rows
      const u16* gA = A + (size_t)(row0 + it * 32 + srow) * K + kt + scol;
      u16* lA = &As[(it * 32 + wave * 8) * BK];
      __builtin_amdgcn_global_load_lds((const __attribute__((address_space(1))) void*)gA,
                                       (__attribute__((address_space(3))) void*)lA, 16, 0, 0);
    }
#pragma unroll
    for (int it = 0; it < 2; ++it) {         // B: 64 rows
      const u16* gB = B + (size_t)(col0 + it * 32 + srow) * K + kt + scol;
      u16* lB = &Bs[(it * 32 + wave * 8) * BK];
      __builtin_amdgcn_global_load_lds((const __attribute__((address_space(1))) void*)gB,
                                       (__attribute__((address_space(3))) void*)lB, 16, 0, 0);
    }
    __syncthreads();                         // implicit vmcnt(0) drain + barrier
#pragma unroll
    for (int kk = 0; kk < 2; ++kk) {
      const int ko = kk * 32 + (lane >> 4) * 8;
      s16x8 af[2], bg[4];
#pragma unroll
      for (int mi = 0; mi < 2; ++mi)
        af[mi] = *(const s16x8*)&As[(wr + mi * 16 + l15) * BK + ko];
#pragma unroll
      for (int ni = 0; ni < 4; ++ni)
        bg[ni] = *(const s16x8*)&Bs[(ni * 16 + l15) * BK + ko];
#pragma unroll
      for (int mi = 0; mi < 2; ++mi)
#pragma unroll
        for (int ni = 0; ni < 4; ++ni)
          acc[mi][ni] = __builtin_amdgcn_mfma_f32_16x16x32_bf16(af[mi], bg[ni], acc[mi][ni], 0, 0, 0);
    }
    __syncthreads();
  }

  const int rq = (lane >> 4) * 4;
  const int cq = l15;

  if (MODE == 3) {
#pragma unroll
    for (int mi = 0; mi < 2; ++mi)
#pragma unroll
      for (int ni = 0; ni < 4; ++ni) {
        const int r = row0 + wr + mi * 16 + rq;
        const int c = col0 + ni * 16 + cq;
#pragma unroll
        for (int t = 0; t < 4; ++t)
          ((float*)Cv)[(size_t)(r + t) * N + c] = acc[mi][ni][t];
      }
  } else if (MODE == 2) {
#pragma unroll
    for (int mi = 0; mi < 2; ++mi)
#pragma unroll
      for (int ni = 0; ni < 4; ++ni) {
        const int r = row0 + wr + mi * 16 + rq;
        const int c = col0 + ni * 16 + cq;
        ushort4 o4;
        o4.x = f2bf(acc[mi][ni][0]); o4.y = f2bf(acc[mi][ni][1]);
        o4.z = f2bf(acc[mi][ni][2]); o4.w = f2bf(acc[mi][ni][3]);
        *(ushort4*)&((u16*)Cv)[(size_t)c * S_LEN + r] = o4;
      }
  } else {
    // MODE 0/1: fused rope. col0 is head-aligned (64): d = ni*16+cq (<32) pairs
    // with d+32 = cols of (mi, ni+2) -> rotate-half pair is thread-local.
    // Fast __sinf/__cosf: reduction err ~2e-4 rad at pos<=2047, << bf16 round.
#pragma unroll
    for (int mi = 0; mi < 2; ++mi) {
#pragma unroll
      for (int t = 0; t < 4; ++t) {
        const int i = row0 + wr + mi * 16 + rq + t;
        const float fpos = (float)pos[i];
#pragma unroll
        for (int ni = 0; ni < 2; ++ni) {
          const int d = ni * 16 + cq;            // 0..31
          const int c = col0 + d;
          const float f = exp2f(-(float)(2 * d) * (1.0f / HD) * L2_1E4);
          const float x1 = acc[mi][ni][t], x2 = acc[mi][ni + 2][t];
          if (MODE == 0) {
            const float scl = (i < CTX) ? 1.0f : 0.25f;
            const float a  = fpos * scl * f;
            const float cs = __cosf(a), sn = __sinf(a);
            u16* Cq = (u16*)Cv;
            Cq[(size_t)i * N + c]      = f2bf((x1 * cs - x2 * sn) * QSCL);
            Cq[(size_t)i * N + c + 32] = f2bf((x2 * cs + x1 * sn) * QSCL);
          } else {
            const float ab = fpos * f, an = fpos * 0.25f * f;
            const float cb_ = __cosf(ab), sb_ = __sinf(ab);
            const float cn_ = __cosf(an), sn_ = __sinf(an);
            ((u16*)Cv)[(size_t)i * N + c]       = f2bf(x1 * cb_ - x2 * sb_);
            ((u16*)Cv)[(size_t)i * N + c + 32]  = f2bf(x2 * cb_ + x1 * sb_);
            ((u16*)Cv2)[(size_t)i * N + c]      = f2bf(x1 * cn_ - x2 * sn_);
            ((u16*)Cv2)[(size_t)i * N + c + 32] = f2bf(x2 * cn_ + x1 * sn_);
          }
        }
      }
    }
  }
}

__global__ __launch_bounds__(256) void gemm_qkv(
    const u16* __restrict__ A, const u16* __restrict__ Wq, const u16* __restrict__ Wk,
    const u16* __restrict__ Wv, u16* __restrict__ Q, u16* __restrict__ Kb,
    u16* __restrict__ Kn, u16* __restrict__ Vt, const int* __restrict__ pos)
{
  __shared__ u16 As[BM * BK];
  __shared__ u16 Bs[BN * BK];
  const int bn = blockIdx.x;
  const int row0 = blockIdx.y * BM;
  if (bn < 32)
    gemm_body<0>(As, Bs, A, Wq, Q, nullptr, HIDN, HIDN, row0, bn * BN, pos);
  else if (bn < 40)
    gemm_body<1>(As, Bs, A, Wk, Kb, Kn, KVW, HIDN, row0, (bn - 32) * BN, pos);
  else
    gemm_body<2>(As, Bs, A, Wv, Vt, nullptr, KVW, HIDN, row0, (bn - 40) * BN, pos);
}

__global__ __launch_bounds__(256) void gemm_out(
    const u16* __restrict__ A, const u16* __restrict__ B, float* __restrict__ C, int N, int K)
{
  __shared__ u16 As[BM * BK];
  __shared__ u16 Bs[BN * BK];
  gemm_body<3>(As, Bs, A, B, C, nullptr, N, K, blockIdx.y * BM, blockIdx.x * BN, 0);
}

// ---------------------------------------------------------------------------
// MFMA flash attention, 32x32 swapped-QK^T, 4-blocks/CU occupancy build:
//  - grid 32 x NH: ONE 64-row q-tile per block, heavy tiles dispatched first
//    (qt = 31 - bx); dynamic HW backfill balances the qt+1-proportional work
//    at 4-deep residency (1024 blocks = 4/CU target).
//  - __launch_bounds__(256) ONLY: round 7's (256,4) min-waves clause forced
//    VGPR=64 -> scratch spills (WRITE_SIZE 2x, occupancy 11%). Natural VGPR
//    is ~112 <= 128, which already permits 4 waves/SIMD; LDS 34.5KB permits
//    4 blocks/CU. Do NOT constrain the allocator (Guideline 6 / m-series).
//  - 4 waves split 2x2 over (row-half x key-half); swapped QK^T = mfma(K,Q),
//    lane owns one q-row, softmax lane-local; P->A-frag via cvt_pk+permlane.
//  - Kns LDS staging dropped: the single CTX-straddle wave gather-loads its
//    Kn fragments from global, issued ahead of QK^T to hide latency.
// ---------------------------------------------------------------------------
#define PAD 8
__global__ __launch_bounds__(256) void attn_mfma(
    const u16* __restrict__ Q, const u16* __restrict__ K, const u16* __restrict__ Kn,
    const u16* __restrict__ Vt, u16* __restrict__ O)
{
  __shared__ __align__(16) u16 Ks[64][HD + PAD];
  __shared__ __align__(16) u16 Vts[HD][64 + PAD];
  __shared__ __align__(16) float Of[64][64];   // cross-wave O merge
  __shared__ float Lf[2][32];                  // cross-wave lsum merge
  __shared__ float Li[2][32];                  // per-row 1/l broadcast

  const int tid  = threadIdx.x;
  const int wave = tid >> 6;
  const int lane = tid & 63;
  const int l31  = lane & 31;
  const int hi   = lane >> 5;
  const int wr   = wave >> 1;                  // row half (0,1)
  const int wk   = wave & 1;                   // key half (0,1)
  const int h    = blockIdx.y;
  const int kh   = h >> 2;
  const int qt   = 31 - (int)blockIdx.x;       // heavy q-tiles dispatch first
  const int rw0  = qt * 64 + wr * 32;          // this wave's 32 q-rows
  const bool mixed_wv = (qt == 31) && (rw0 + 31 >= CTX);

  // staging map: 2 iters x 256 threads x 16B cover one 64x64 bf16 tile
  int sa[2], sb[2];
#pragma unroll
  for (int it = 0; it < 2; ++it) {
    const int u = it * 256 + tid;
    sa[it] = u >> 3;
    sb[it] = (u & 7) * 8;
  }

  // persistent Q B-frags: B[n=q=l31][k=d = i*16 + hi*8 + j]
  s16x8 bq[4];
#pragma unroll
  for (int i = 0; i < 4; ++i)
    bq[i] = *(const s16x8*)(Q + (size_t)(rw0 + l31) * HIDN + h * HD + i * 16 + hi * 8);

  f32x16 acc0 = {};      // O[q][d], d = l31       (rows in reg pattern)
  f32x16 acc1 = {};      // O[q][d], d = l31 + 32
  float lsum = 0.f;      // partial row sum (this lane's 16 keys)

  const int ntiles = qt + 1;
  s16x8 kr[2], vr[2];
#pragma unroll
  for (int it = 0; it < 2; ++it) {
    kr[it] = *(const s16x8*)(K  + (size_t)sa[it] * KVW + kh * HD + sb[it]);
    vr[it] = *(const s16x8*)(Vt + (size_t)(kh * HD + sa[it]) * S_LEN + sb[it]);
  }

  // lane-resolved Kn fragment base for the straddle wave (gather path)
  const u16* Knp = Kn + (size_t)(wk * 32 + l31) * KVW + kh * HD;

  for (int t = 0; t < ntiles; ++t) {
    const int jt = t * 64;
    __syncthreads();                        // LDS free (prev tile's reads done)
#pragma unroll
    for (int it = 0; it < 2; ++it) {
      *(s16x8*)&Ks[sa[it]][sb[it]]  = kr[it];
      *(s16x8*)&Vts[sa[it]][sb[it]] = vr[it];
    }
    __syncthreads();                        // LDS ready
    if (t + 1 < ntiles) {                   // prefetch next tile (overlaps compute)
      const int jn = jt + 64;
#pragma unroll
      for (int it = 0; it < 2; ++it) {
        kr[it] = *(const s16x8*)(K  + (size_t)(jn + sa[it]) * KVW + kh * HD + sb[it]);
        vr[it] = *(const s16x8*)(Vt + (size_t)(kh * HD + sa[it]) * S_LEN + jn + sb[it]);
      }
    }

    const int j0 = jt + wk * 32;            // this wave's 32-key group
    if (j0 > rw0 + 31) continue;            // fully masked for this wave
    const bool needmask = (j0 + 31 > rw0);  // straddles the diagonal

    // straddle wave: issue Kn gather loads early (overlap with QK^T MFMAs)
    s16x8 akn[4];
    if (mixed_wv) {
      const u16* p = Knp + (size_t)jt * KVW;
#pragma unroll
      for (int i = 0; i < 4; ++i) akn[i] = *(const s16x8*)(p + i * 16 + hi * 8);
    }

    // swapped QK^T: D[m=key (reg pattern)][n=q (l31)]
    f32x16 sc = {};
#pragma unroll
    for (int i = 0; i < 4; ++i) {
      const s16x8 ak = *(const s16x8*)&Ks[wk * 32 + l31][i * 16 + hi * 8];
      sc = __builtin_amdgcn_mfma_f32_32x32x16_bf16(ak, bq[i], sc, 0, 0, 0);
    }
    if (mixed_wv) {                         // rows straddle CTX: also narrow
      f32x16 scn = {};
#pragma unroll
      for (int i = 0; i < 4; ++i)
        scn = __builtin_amdgcn_mfma_f32_32x32x16_bf16(akn[i], bq[i], scn, 0, 0, 0);
      const bool nar = (rw0 + l31) >= CTX;  // per-lane: q-row selects rope
#pragma unroll
      for (int r = 0; r < 16; ++r) sc[r] = nar ? scn[r] : sc[r];
    }

    // lane-local softmax: p = exp2(min(s,80)) (Q pre-scaled by log2e/8)
    float p[16];
#pragma unroll
    for (int r = 0; r < 16; ++r) {
      float e = __builtin_amdgcn_exp2f(fminf(sc[r], 80.f));
      if (needmask) {
        const int key = j0 + (r & 3) + 8 * (r >> 2) + 4 * hi;
        e = (key > rw0 + l31) ? 0.f : e;
      }
      p[r] = e;
      lsum += e;
    }

    // pack p -> bf16 pairs: c[blk][j] = keys 8*blk + 4*hi + {2j, 2j+1}
    unsigned int c[4][2];
#pragma unroll
    for (int blk = 0; blk < 4; ++blk) {
      c[blk][0] = cvt_pk_bf16(p[4 * blk + 0], p[4 * blk + 1]);
      c[blk][1] = cvt_pk_bf16(p[4 * blk + 2], p[4 * blk + 3]);
    }

    // per 16-key slice s: swap halves -> A-frag words, then 2 PV MFMAs
#pragma unroll
    for (int s = 0; s < 2; ++s) {
      unsigned int w0 = c[2 * s][0], w2 = c[2 * s + 1][0];
      unsigned int w1 = c[2 * s][1], w3 = c[2 * s + 1][1];
      asm("v_permlane32_swap_b32 %0, %1" : "+v"(w0), "+v"(w2));
      asm("v_permlane32_swap_b32 %0, %1" : "+v"(w1), "+v"(w3));
      union { unsigned int u[4]; s16x8 v; } af;
      af.u[0] = w0; af.u[1] = w1; af.u[2] = w2; af.u[3] = w3;
      const int kc = wk * 32 + s * 16 + hi * 8;
      const s16x8 v0 = *(const s16x8*)&Vts[l31][kc];
      const s16x8 v1 = *(const s16x8*)&Vts[32 + l31][kc];
      acc0 = __builtin_amdgcn_mfma_f32_32x32x16_bf16(af.v, v0, acc0, 0, 0, 0);
      acc1 = __builtin_amdgcn_mfma_f32_32x32x16_bf16(af.v, v1, acc1, 0, 0, 0);
    }
  }

  // ---- cross-wave merge over key halves + epilogue ----
  lsum += __shfl_xor(lsum, 32, 64);         // combine hi halves: row sum over
                                            // this wave's 32 keys, row = rw0+l31
  __syncthreads();                          // all compute done; LDS tiles free
  if (wk == 1) {
#pragma unroll
    for (int r = 0; r < 16; ++r) {
      const int rl = (r & 3) + 8 * (r >> 2) + 4 * hi;
      Of[wr * 32 + rl][l31]      = acc0[r];
      Of[wr * 32 + rl][l31 + 32] = acc1[r];
    }
    if (hi == 0) Lf[wr][l31] = lsum;
  }
  __syncthreads();
  if (wk == 0) {
    const float tot = lsum + Lf[wr][l31];
    const float inv = 1.0f / fmaxf(tot, 1e-30f);
    if (hi == 0) Li[wr][l31] = inv;         // same-wave write->read (in-order LDS)
#pragma unroll
    for (int r = 0; r < 16; ++r) {
      const int rl = (r & 3) + 8 * (r >> 2) + 4 * hi;
      const float iv = Li[wr][rl];
      const size_t o = (size_t)(rw0 + rl) * HIDN + h * HD + l31;
      O[o]      = f2bf((acc0[r] + Of[wr * 32 + rl][l31])      * iv);
      O[o + 32] = f2bf((acc1[r] + Of[wr * 32 + rl][l31 + 32]) * iv);
    }
  }
}

// ---------------------------------------------------------------------------
extern "C" void kernel_launch(void* const* d_in, const int* in_sizes, int n_in,
                              void* d_out, int out_size, void* d_ws, size_t ws_size,
                              hipStream_t stream)
{
  const float* hidden = (const float*)d_in[0];
  const int* pos      = (const int*)d_in[2];   // d_in[1] mask: pure causal, unused
  const float* Wq = (const float*)d_in[3];
  const float* Wk = (const float*)d_in[4];
  const float* Wv = (const float*)d_in[5];
  const float* Wo = (const float*)d_in[6];
  float* out = (float*)d_out;

  char* ws = (char*)d_ws;
  u16* Qb  = (u16*)(ws);                    // 8 MB  bf16 Q (roped+scaled by gemm)
  u16* Kbb = (u16*)(ws + (8u  << 20));      // 2 MB  bf16 boost K (roped by gemm)
  u16* Knb = (u16*)(ws + (10u << 20));      // 2 MB  bf16 narrow K
  u16* Vtb = (u16*)(ws + (12u << 20));      // 2 MB  bf16 V transposed [kv_col][seq]
  u16* Ab  = (u16*)(ws + (14u << 20));      // 8 MB  bf16 attention output
  u16* Hb  = (u16*)(ws + (22u << 20));      // 8 MB  bf16 hidden
  u16* Wqb = (u16*)(ws + (30u << 20));      // 8 MB  bf16 Wq
  u16* Wkb = (u16*)(ws + (38u << 20));      // 2 MB  bf16 Wk
  u16* Wvb = (u16*)(ws + (40u << 20));      // 2 MB  bf16 Wv
  u16* Wob = (u16*)(ws + (42u << 20));      // 8 MB  bf16 Wo  => 50 MB total

  conv_all<<<dim3(14336), 256, 0, stream>>>(hidden, Wq, Wk, Wv, Wo, Hb, Wqb, Wkb, Wvb, Wob);
  gemm_qkv<<<dim3(48, 16), 256, 0, stream>>>(Hb, Wqb, Wkb, Wvb, Qb, Kbb, Knb, Vtb, pos);
  attn_mfma<<<dim3(32, NH), 256, 0, stream>>>(Qb, Kbb, Knb, Vtb, Ab);
  gemm_out<<<dim3(32, 16), 256, 0, stream>>>(Ab, Wob, out, HIDN, HIDN);
}

// Round 9
// 261.887 us; speedup vs baseline: 1.1592x; 1.1342x over previous
//
#include <hip/hip_runtime.h>
#include <math.h>

#define S_LEN 2048
#define HIDN  2048
#define NH    32
#define NKV   8
#define HD    64
#define KVW   (NKV * HD)     // 512
#define CTX   (S_LEN - 10)   // 2038: rows < CTX use boost rope, rows >= CTX use narrow

typedef unsigned short u16;
typedef __attribute__((ext_vector_type(4))) float f32x4;
typedef __attribute__((ext_vector_type(16))) float f32x16;
typedef __attribute__((ext_vector_type(8))) short s16x8;

#define QSCL 0.18033688011112042f    // 0.125 * log2(e): attn uses exp2(score)
#define L2_1E4 13.287712379549449f   // log2(10000)

__device__ __forceinline__ float bf2f(u16 u) {
  union { unsigned int i; float f; } v; v.i = ((unsigned int)u) << 16; return v.f;
}
__device__ __forceinline__ u16 f2bf(float f) {
  union { float f; unsigned int i; } v; v.f = f;
  unsigned int r = v.i + 0x7fffu + ((v.i >> 16) & 1u);
  return (u16)(r >> 16);
}
__device__ __forceinline__ unsigned int cvt_pk_bf16(float a, float b) {
  unsigned int d;
  asm("v_cvt_pk_bf16_f32 %0, %1, %2" : "=v"(d) : "v"(a), "v"(b));
  return d;
}

// ---------------------------------------------------------------------------
// fp32 -> bf16 conversion: hidden + Wq + Wk + Wv + Wo in one launch.
// ---------------------------------------------------------------------------
__global__ __launch_bounds__(256) void conv_all(
    const float* __restrict__ h,  const float* __restrict__ wq,
    const float* __restrict__ wk, const float* __restrict__ wv,
    const float* __restrict__ wo,
    u16* __restrict__ Hb, u16* __restrict__ Wqb, u16* __restrict__ Wkb,
    u16* __restrict__ Wvb, u16* __restrict__ Wob)
{
  const int i = blockIdx.x * 256 + threadIdx.x;   // one float4 per thread
  const float* src; u16* dst; int off;
  if      (i < 1048576) { src = h;  dst = Hb;  off = i; }
  else if (i < 2097152) { src = wq; dst = Wqb; off = i - 1048576; }
  else if (i < 2359296) { src = wk; dst = Wkb; off = i - 2097152; }
  else if (i < 2621440) { src = wv; dst = Wvb; off = i - 2359296; }
  else                  { src = wo; dst = Wob; off = i - 2621440; }
  const float4 f4 = ((const float4*)src)[off];
  ushort4 o4;
  o4.x = f2bf(f4.x); o4.y = f2bf(f4.y); o4.z = f2bf(f4.z); o4.w = f2bf(f4.w);
  ((ushort4*)dst)[off] = o4;
}

// ---------------------------------------------------------------------------
// GEMM: C[M,N] = A[M,K] * B[N,K]^T (bf16 in, fp32 accum), 128x64 tile, BK=64.
// Single-buffered m97-style loop (proven; dbuf/sched_barrier both measured
// regressions). 768/512 blocks -> 3/2 per CU, m114 implicit overlap.
// MODE: 0 = Q (fused rope boost/narrow + QSCL, bf16)
//       1 = K (fused rope dual: boost -> Cv, narrow -> Cv2, bf16)
//       2 = V (write C^T, row stride S_LEN, bf16)
//       3 = OUT (f32)
// ---------------------------------------------------------------------------
#define BM 128
#define BN 64
#define BK 64

template<int MODE>
__device__ __forceinline__ void gemm_body(
    u16* __restrict__ As, u16* __restrict__ Bs,
    const u16* __restrict__ A, const u16* __restrict__ B,
    void* __restrict__ Cv, void* __restrict__ Cv2,
    int N, int K, int row0, int col0, const int* __restrict__ pos)
{
  const int tid  = threadIdx.x;
  const int wave = tid >> 6;
  const int lane = tid & 63;
  const int l15  = lane & 15;
  const int wr   = wave * 32;          // wave's 32 output rows

  f32x4 acc[2][4] = {};

  const int srow = wave * 8 + (lane >> 3);   // 0..31
  const int scol = (lane & 7) * 8;

  for (int kt = 0; kt < K; kt += BK) {
#pragma unroll
    for (int it = 0; it < 4; ++it) {         // A: 128 rows
      const u16* gA = A + (size_t)(row0 + it * 32 + srow) * K + kt + scol;
      u16* lA = &As[(it * 32 + wave * 8) * BK];
      __builtin_amdgcn_global_load_lds((const __attribute__((address_space(1))) void*)gA,
                                       (__attribute__((address_space(3))) void*)lA, 16, 0, 0);
    }
#pragma unroll
    for (int it = 0; it < 2; ++it) {         // B: 64 rows
      const u16* gB = B + (size_t)(col0 + it * 32 + srow) * K + kt + scol;
      u16* lB = &Bs[(it * 32 + wave * 8) * BK];
      __builtin_amdgcn_global_load_lds((const __attribute__((address_space(1))) void*)gB,
                                       (__attribute__((address_space(3))) void*)lB, 16, 0, 0);
    }
    __syncthreads();                         // implicit vmcnt(0) drain + barrier
#pragma unroll
    for (int kk = 0; kk < 2; ++kk) {
      const int ko = kk * 32 + (lane >> 4) * 8;
      s16x8 af[2], bg[4];
#pragma unroll
      for (int mi = 0; mi < 2; ++mi)
        af[mi] = *(const s16x8*)&As[(wr + mi * 16 + l15) * BK + ko];
#pragma unroll
      for (int ni = 0; ni < 4; ++ni)
        bg[ni] = *(const s16x8*)&Bs[(ni * 16 + l15) * BK + ko];
#pragma unroll
      for (int mi = 0; mi < 2; ++mi)
#pragma unroll
        for (int ni = 0; ni < 4; ++ni)
          acc[mi][ni] = __builtin_amdgcn_mfma_f32_16x16x32_bf16(af[mi], bg[ni], acc[mi][ni], 0, 0, 0);
    }
    __syncthreads();
  }

  const int rq = (lane >> 4) * 4;
  const int cq = l15;

  if (MODE == 3) {
#pragma unroll
    for (int mi = 0; mi < 2; ++mi)
#pragma unroll
      for (int ni = 0; ni < 4; ++ni) {
        const int r = row0 + wr + mi * 16 + rq;
        const int c = col0 + ni * 16 + cq;
#pragma unroll
        for (int t = 0; t < 4; ++t)
          ((float*)Cv)[(size_t)(r + t) * N + c] = acc[mi][ni][t];
      }
  } else if (MODE == 2) {
#pragma unroll
    for (int mi = 0; mi < 2; ++mi)
#pragma unroll
      for (int ni = 0; ni < 4; ++ni) {
        const int r = row0 + wr + mi * 16 + rq;
        const int c = col0 + ni * 16 + cq;
        ushort4 o4;
        o4.x = f2bf(acc[mi][ni][0]); o4.y = f2bf(acc[mi][ni][1]);
        o4.z = f2bf(acc[mi][ni][2]); o4.w = f2bf(acc[mi][ni][3]);
        *(ushort4*)&((u16*)Cv)[(size_t)c * S_LEN + r] = o4;
      }
  } else {
    // MODE 0/1: fused rope. col0 is head-aligned (64): d = ni*16+cq (<32) pairs
    // with d+32 = cols of (mi, ni+2) -> rotate-half pair is thread-local.
    // Fast __sinf/__cosf: reduction err ~2e-4 rad at pos<=2047, << bf16 round.
#pragma unroll
    for (int mi = 0; mi < 2; ++mi) {
#pragma unroll
      for (int t = 0; t < 4; ++t) {
        const int i = row0 + wr + mi * 16 + rq + t;
        const float fpos = (float)pos[i];
#pragma unroll
        for (int ni = 0; ni < 2; ++ni) {
          const int d = ni * 16 + cq;            // 0..31
          const int c = col0 + d;
          const float f = exp2f(-(float)(2 * d) * (1.0f / HD) * L2_1E4);
          const float x1 = acc[mi][ni][t], x2 = acc[mi][ni + 2][t];
          if (MODE == 0) {
            const float scl = (i < CTX) ? 1.0f : 0.25f;
            const float a  = fpos * scl * f;
            const float cs = __cosf(a), sn = __sinf(a);
            u16* Cq = (u16*)Cv;
            Cq[(size_t)i * N + c]      = f2bf((x1 * cs - x2 * sn) * QSCL);
            Cq[(size_t)i * N + c + 32] = f2bf((x2 * cs + x1 * sn) * QSCL);
          } else {
            const float ab = fpos * f, an = fpos * 0.25f * f;
            const float cb_ = __cosf(ab), sb_ = __sinf(ab);
            const float cn_ = __cosf(an), sn_ = __sinf(an);
            ((u16*)Cv)[(size_t)i * N + c]       = f2bf(x1 * cb_ - x2 * sb_);
            ((u16*)Cv)[(size_t)i * N + c + 32]  = f2bf(x2 * cb_ + x1 * sb_);
            ((u16*)Cv2)[(size_t)i * N + c]      = f2bf(x1 * cn_ - x2 * sn_);
            ((u16*)Cv2)[(size_t)i * N + c + 32] = f2bf(x2 * cn_ + x1 * sn_);
          }
        }
      }
    }
  }
}

__global__ __launch_bounds__(256) void gemm_qkv(
    const u16* __restrict__ A, const u16* __restrict__ Wq, const u16* __restrict__ Wk,
    const u16* __restrict__ Wv, u16* __restrict__ Q, u16* __restrict__ Kb,
    u16* __restrict__ Kn, u16* __restrict__ Vt, const int* __restrict__ pos)
{
  __shared__ u16 As[BM * BK];
  __shared__ u16 Bs[BN * BK];
  const int bn = blockIdx.x;
  const int row0 = blockIdx.y * BM;
  if (bn < 32)
    gemm_body<0>(As, Bs, A, Wq, Q, nullptr, HIDN, HIDN, row0, bn * BN, pos);
  else if (bn < 40)
    gemm_body<1>(As, Bs, A, Wk, Kb, Kn, KVW, HIDN, row0, (bn - 32) * BN, pos);
  else
    gemm_body<2>(As, Bs, A, Wv, Vt, nullptr, KVW, HIDN, row0, (bn - 40) * BN, pos);
}

__global__ __launch_bounds__(256) void gemm_out(
    const u16* __restrict__ A, const u16* __restrict__ B, float* __restrict__ C, int N, int K)
{
  __shared__ u16 As[BM * BK];
  __shared__ u16 Bs[BN * BK];
  gemm_body<3>(As, Bs, A, B, C, nullptr, N, K, blockIdx.y * BM, blockIdx.x * BN, 0);
}

// ---------------------------------------------------------------------------
// MFMA flash attention, 32x32 swapped-QK^T, 8-wave balanced high-TLP build:
//  - grid 16 x NH, 512 threads: block p runs q-tile pair {31-p, p} (triangle
//    balance) with 128 keys per tile-iter -> every block = EXACTLY 17 iters.
//    512 blocks x 8 waves = 4096 waves = 16/CU = 4/SIMD (2x the 63us builds;
//    round-8 showed imbalanced grids waste the added residency in the tail).
//  - 8 waves = (row-half wr) x (key-subtile ws) x (key-half wk): each wave
//    the proven 32 rows x 32 keys job: swapped QK^T = mfma(K,Q), lane-local
//    softmax, P->A-frag via cvt_pk+permlane (rounds 2-5 machinery verbatim).
//  - 4-way (O,l) merge per row-half through Of[3][2][32][64] f32 (49KB),
//    UNION'd over the dead K/V staging LDS (staging finished before merge).
//    Total LDS 49KB -> 2 blocks/CU. No launch-bounds min-waves clause
//    (round-7 spill lesson); VGPR must stay <=128 for 4/SIMD.
//  - CTX-straddle waves (qt==31, wr==1) gather Kn fragments from global
//    (round-8 verified), issued ahead of QK^T.
// ---------------------------------------------------------------------------
#define KS_OFF   0
#define VT_OFF   18432                 // Ks: 128*72*2
#define OF_OFF   0
#define LF_OFF   49152                 // Of: 3*2*32*64*4
#define LI_OFF   49920
#define SMEM_SZ  50176

__global__ __launch_bounds__(512) void attn_mfma(
    const u16* __restrict__ Q, const u16* __restrict__ K, const u16* __restrict__ Kn,
    const u16* __restrict__ Vt, u16* __restrict__ O)
{
  __shared__ __align__(16) char smem[SMEM_SZ];
  u16 (*Ks)[72]           = (u16 (*)[72])(smem + KS_OFF);     // [128][72]
  u16 (*Vts)[136]         = (u16 (*)[136])(smem + VT_OFF);    // [64][136]
  float (*Of)[2][32][64]  = (float (*)[2][32][64])(smem + OF_OFF);  // [3][..]
  float (*Lf)[2][32]      = (float (*)[2][32])(smem + LF_OFF);      // [3][..]
  float (*Li)[32]         = (float (*)[32])(smem + LI_OFF);         // [2][32]

  const int tid  = threadIdx.x;
  const int wave = tid >> 6;
  const int lane = tid & 63;
  const int l31  = lane & 31;
  const int hi   = lane >> 5;
  const int wr   = wave >> 2;                  // row half (0,1)
  const int ws   = (wave >> 1) & 1;            // 64-key subtile (0,1)
  const int wk   = wave & 1;                   // 32-key half (0,1)
  const int mj   = (ws << 1) | wk;             // merge index 0..3
  const int h    = blockIdx.y;
  const int kh   = h >> 2;
  const int pr   = blockIdx.x;                 // pair index 0..15
  const int kboff = ws * 64 + wk * 32;         // wave key offset within 128

  // staging maps: 2 iters x 512 threads x 16B each for K (128x64) and V (64x128)
  int kra[2], krb[2], vra[2], vrb[2];
#pragma unroll
  for (int it = 0; it < 2; ++it) {
    const int u = it * 512 + tid;
    kra[it] = u >> 3;  krb[it] = (u & 7) * 8;
    vra[it] = u >> 4;  vrb[it] = (u & 15) * 8;
  }

  // lane-resolved Kn fragment base for the straddle waves (gather path)
  const u16* Knp = Kn + (size_t)(kboff + l31) * KVW + kh * HD;

  for (int ph = 0; ph < 2; ++ph) {
    const int qt  = ph ? pr : 31 - pr;         // heavy tile first
    const int rw0 = qt * 64 + wr * 32;         // this wave's 32 q-rows
    const bool mixed_wv = (qt == 31) && (rw0 + 31 >= CTX);

    // persistent Q B-frags: B[n=q=l31][k=d = i*16 + hi*8 + j]
    s16x8 bq[4];
#pragma unroll
    for (int i = 0; i < 4; ++i)
      bq[i] = *(const s16x8*)(Q + (size_t)(rw0 + l31) * HIDN + h * HD + i * 16 + hi * 8);

    f32x16 acc0 = {};      // O[q][d], d = l31       (rows in reg pattern)
    f32x16 acc1 = {};      // O[q][d], d = l31 + 32
    float lsum = 0.f;      // partial row sum (this lane's 16 keys)

    const int n128 = (qt + 2) >> 1;            // 128-key iters this phase
    s16x8 kr[2], vr[2];
#pragma unroll
    for (int it = 0; it < 2; ++it) {
      kr[it] = *(const s16x8*)(K  + (size_t)kra[it] * KVW + kh * HD + krb[it]);
      vr[it] = *(const s16x8*)(Vt + (size_t)(kh * HD + vra[it]) * S_LEN + vrb[it]);
    }

    for (int t = 0; t < n128; ++t) {
      const int jt = t * 128;
      __syncthreads();                        // LDS free (prev reads / Of done)
#pragma unroll
      for (int it = 0; it < 2; ++it) {
        *(s16x8*)&Ks[kra[it]][krb[it]]  = kr[it];
        *(s16x8*)&Vts[vra[it]][vrb[it]] = vr[it];
      }
      __syncthreads();                        // LDS ready
      if (t + 1 < n128) {                     // prefetch next 128-key tile
        const int jn = jt + 128;
#pragma unroll
        for (int it = 0; it < 2; ++it) {
          kr[it] = *(const s16x8*)(K  + (size_t)(jn + kra[it]) * KVW + kh * HD + krb[it]);
          vr[it] = *(const s16x8*)(Vt + (size_t)(kh * HD + vra[it]) * S_LEN + jn + vrb[it]);
        }
      }

      const int kb = jt + kboff;              // this wave's 32-key group
      if (kb > rw0 + 31) continue;            // fully masked for this wave
      const bool needmask = (kb + 31 > rw0);  // straddles the diagonal

      // straddle wave: issue Kn gather loads early (overlap with QK^T MFMAs)
      s16x8 akn[4];
      if (mixed_wv) {
        const u16* p = Knp + (size_t)jt * KVW;
#pragma unroll
        for (int i = 0; i < 4; ++i) akn[i] = *(const s16x8*)(p + i * 16 + hi * 8);
      }

      // swapped QK^T: D[m=key (reg pattern)][n=q (l31)]
      f32x16 sc = {};
#pragma unroll
      for (int i = 0; i < 4; ++i) {
        const s16x8 ak = *(const s16x8*)&Ks[kboff + l31][i * 16 + hi * 8];
        sc = __builtin_amdgcn_mfma_f32_32x32x16_bf16(ak, bq[i], sc, 0, 0, 0);
      }
      if (mixed_wv) {                         // rows straddle CTX: also narrow
        f32x16 scn = {};
#pragma unroll
        for (int i = 0; i < 4; ++i)
          scn = __builtin_amdgcn_mfma_f32_32x32x16_bf16(akn[i], bq[i], scn, 0, 0, 0);
        const bool nar = (rw0 + l31) >= CTX;  // per-lane: q-row selects rope
#pragma unroll
        for (int r = 0; r < 16; ++r) sc[r] = nar ? scn[r] : sc[r];
      }

      // lane-local softmax: p = exp2(min(s,80)) (Q pre-scaled by log2e/8)
      float p[16];
#pragma unroll
      for (int r = 0; r < 16; ++r) {
        float e = __builtin_amdgcn_exp2f(fminf(sc[r], 80.f));
        if (needmask) {
          const int key = kb + (r & 3) + 8 * (r >> 2) + 4 * hi;
          e = (key > rw0 + l31) ? 0.f : e;
        }
        p[r] = e;
        lsum += e;
      }

      // pack p -> bf16 pairs: c[blk][j] = keys 8*blk + 4*hi + {2j, 2j+1}
      unsigned int c[4][2];
#pragma unroll
      for (int blk = 0; blk < 4; ++blk) {
        c[blk][0] = cvt_pk_bf16(p[4 * blk + 0], p[4 * blk + 1]);
        c[blk][1] = cvt_pk_bf16(p[4 * blk + 2], p[4 * blk + 3]);
      }

      // per 16-key slice s: swap halves -> A-frag words, then 2 PV MFMAs
#pragma unroll
      for (int s = 0; s < 2; ++s) {
        unsigned int w0 = c[2 * s][0], w2 = c[2 * s + 1][0];
        unsigned int w1 = c[2 * s][1], w3 = c[2 * s + 1][1];
        asm("v_permlane32_swap_b32 %0, %1" : "+v"(w0), "+v"(w2));
        asm("v_permlane32_swap_b32 %0, %1" : "+v"(w1), "+v"(w3));
        union { unsigned int u[4]; s16x8 v; } af;
        af.u[0] = w0; af.u[1] = w1; af.u[2] = w2; af.u[3] = w3;
        const int kc = kboff + s * 16 + hi * 8;
        const s16x8 v0 = *(const s16x8*)&Vts[l31][kc];
        const s16x8 v1 = *(const s16x8*)&Vts[32 + l31][kc];
        acc0 = __builtin_amdgcn_mfma_f32_32x32x16_bf16(af.v, v0, acc0, 0, 0, 0);
        acc1 = __builtin_amdgcn_mfma_f32_32x32x16_bf16(af.v, v1, acc1, 0, 0, 0);
      }
    }

    // ---- 4-way cross-wave merge per row-half (Of union'd over staging) ----
    lsum += __shfl_xor(lsum, 32, 64);         // combine hi halves: row sum over
                                              // this wave's 32 keys, row = rw0+l31
    __syncthreads();                          // staging reads done -> Of safe
    if (mj) {
#pragma unroll
      for (int r = 0; r < 16; ++r) {
        const int rl = (r & 3) + 8 * (r >> 2) + 4 * hi;
        Of[mj - 1][wr][rl][l31]      = acc0[r];
        Of[mj - 1][wr][rl][l31 + 32] = acc1[r];
      }
      if (hi == 0) Lf[mj - 1][wr][l31] = lsum;
    }
    __syncthreads();
    if (mj == 0) {
      const float tot = lsum + Lf[0][wr][l31] + Lf[1][wr][l31] + Lf[2][wr][l31];
      const float inv = 1.0f / fmaxf(tot, 1e-30f);
      if (hi == 0) Li[wr][l31] = inv;         // same-wave write->read (in-order LDS)
#pragma unroll
      for (int r = 0; r < 16; ++r) {
        const int rl = (r & 3) + 8 * (r >> 2) + 4 * hi;
        const float iv = Li[wr][rl];
        const float o0 = acc0[r] + Of[0][wr][rl][l31]      + Of[1][wr][rl][l31]      + Of[2][wr][rl][l31];
        const float o1 = acc1[r] + Of[0][wr][rl][l31 + 32] + Of[1][wr][rl][l31 + 32] + Of[2][wr][rl][l31 + 32];
        const size_t o = (size_t)(rw0 + rl) * HIDN + h * HD + l31;
        O[o]      = f2bf(o0 * iv);
        O[o + 32] = f2bf(o1 * iv);
      }
    }
    // next phase's loop-top __syncthreads orders these Of reads before any
    // wave's phase-2 staging store into the same (union'd) LDS.
  }
}

// ---------------------------------------------------------------------------
extern "C" void kernel_launch(void* const* d_in, const int* in_sizes, int n_in,
                              void* d_out, int out_size, void* d_ws, size_t ws_size,
                              hipStream_t stream)
{
  const float* hidden = (const float*)d_in[0];
  const int* pos      = (const int*)d_in[2];   // d_in[1] mask: pure causal, unused
  const float* Wq = (const float*)d_in[3];
  const float* Wk = (const float*)d_in[4];
  const float* Wv = (const float*)d_in[5];
  const float* Wo = (const float*)d_in[6];
  float* out = (float*)d_out;

  char* ws = (char*)d_ws;
  u16* Qb  = (u16*)(ws);                    // 8 MB  bf16 Q (roped+scaled by gemm)
  u16* Kbb = (u16*)(ws + (8u  << 20));      // 2 MB  bf16 boost K (roped by gemm)
  u16* Knb = (u16*)(ws + (10u << 20));      // 2 MB  bf16 narrow K
  u16* Vtb = (u16*)(ws + (12u << 20));      // 2 MB  bf16 V transposed [kv_col][seq]
  u16* Ab  = (u16*)(ws + (14u << 20));      // 8 MB  bf16 attention output
  u16* Hb  = (u16*)(ws + (22u << 20));      // 8 MB  bf16 hidden
  u16* Wqb = (u16*)(ws + (30u << 20));      // 8 MB  bf16 Wq
  u16* Wkb = (u16*)(ws + (38u << 20));      // 2 MB  bf16 Wk
  u16* Wvb = (u16*)(ws + (40u << 20));      // 2 MB  bf16 Wv
  u16* Wob = (u16*)(ws + (42u << 20));      // 8 MB  bf16 Wo  => 50 MB total

  conv_all<<<dim3(14336), 256, 0, stream>>>(hidden, Wq, Wk, Wv, Wo, Hb, Wqb, Wkb, Wvb, Wob);
  gemm_qkv<<<dim3(48, 16), 256, 0, stream>>>(Hb, Wqb, Wkb, Wvb, Qb, Kbb, Knb, Vtb, pos);
  attn_mfma<<<dim3(16, NH), 512, 0, stream>>>(Qb, Kbb, Knb, Vtb, Ab);
  gemm_out<<<dim3(32, 16), 256, 0, stream>>>(Ab, Wob, out, HIDN, HIDN);
}

// Round 10
// 233.648 us; speedup vs baseline: 1.2993x; 1.1209x over previous
//
#include <hip/hip_runtime.h>
#include <math.h>

#define S_LEN 2048
#define HIDN  2048
#define NH    32
#define NKV   8
#define HD    64
#define KVW   (NKV * HD)     // 512
#define CTX   (S_LEN - 10)   // 2038: rows < CTX use boost rope, rows >= CTX use narrow

typedef unsigned short u16;
typedef __attribute__((ext_vector_type(4))) float f32x4;
typedef __attribute__((ext_vector_type(16))) float f32x16;
typedef __attribute__((ext_vector_type(8))) short s16x8;

#define QSCL 0.18033688011112042f    // 0.125 * log2(e): attn uses exp2(score)
#define L2_1E4 13.287712379549449f   // log2(10000)

__device__ __forceinline__ float bf2f(u16 u) {
  union { unsigned int i; float f; } v; v.i = ((unsigned int)u) << 16; return v.f;
}
__device__ __forceinline__ u16 f2bf(float f) {
  union { float f; unsigned int i; } v; v.f = f;
  unsigned int r = v.i + 0x7fffu + ((v.i >> 16) & 1u);
  return (u16)(r >> 16);
}
__device__ __forceinline__ unsigned int cvt_pk_bf16(float a, float b) {
  unsigned int d;
  asm("v_cvt_pk_bf16_f32 %0, %1, %2" : "=v"(d) : "v"(a), "v"(b));
  return d;
}

// ---------------------------------------------------------------------------
// fp32 -> bf16 conversion: hidden + Wq + Wk + Wv + Wo in one launch.
// ---------------------------------------------------------------------------
__global__ __launch_bounds__(256) void conv_all(
    const float* __restrict__ h,  const float* __restrict__ wq,
    const float* __restrict__ wk, const float* __restrict__ wv,
    const float* __restrict__ wo,
    u16* __restrict__ Hb, u16* __restrict__ Wqb, u16* __restrict__ Wkb,
    u16* __restrict__ Wvb, u16* __restrict__ Wob)
{
  const int i = blockIdx.x * 256 + threadIdx.x;   // one float4 per thread
  const float* src; u16* dst; int off;
  if      (i < 1048576) { src = h;  dst = Hb;  off = i; }
  else if (i < 2097152) { src = wq; dst = Wqb; off = i - 1048576; }
  else if (i < 2359296) { src = wk; dst = Wkb; off = i - 2097152; }
  else if (i < 2621440) { src = wv; dst = Wvb; off = i - 2359296; }
  else                  { src = wo; dst = Wob; off = i - 2621440; }
  const float4 f4 = ((const float4*)src)[off];
  ushort4 o4;
  o4.x = f2bf(f4.x); o4.y = f2bf(f4.y); o4.z = f2bf(f4.z); o4.w = f2bf(f4.w);
  ((ushort4*)dst)[off] = o4;
}

// ---------------------------------------------------------------------------
// GEMM: C[M,N] = A[M,K] * B[N,K]^T (bf16 in, fp32 accum), 128x64 tile, BK=64.
// Single-buffered m97-style loop (proven; dbuf/sched_barrier both measured
// regressions). 768/512 blocks -> 3/2 per CU, m114 implicit overlap.
// NEW (T2, rule #21): XOR bank-swizzle with LINEAR LDS dest (global_load_lds
// requires it): lane fetches global slot (lane&7)^(lane>>3) so LDS slot s of
// row r holds global slot s^(r&7); reads XOR the slot back. Kills the 16-way
// conflict of 128B-stride rows (r3 measured SQ_LDS_BANK_CONFLICT=9.4M).
// MODE: 0 = Q (fused rope boost/narrow + QSCL, bf16)
//       1 = K (fused rope dual: boost -> Cv, narrow -> Cv2, bf16)
//       2 = V (write C^T, row stride S_LEN, bf16)
//       3 = OUT (f32)
// ---------------------------------------------------------------------------
#define BM 128
#define BN 64
#define BK 64

template<int MODE>
__device__ __forceinline__ void gemm_body(
    u16* __restrict__ As, u16* __restrict__ Bs,
    const u16* __restrict__ A, const u16* __restrict__ B,
    void* __restrict__ Cv, void* __restrict__ Cv2,
    int N, int K, int row0, int col0, const int* __restrict__ pos)
{
  const int tid  = threadIdx.x;
  const int wave = tid >> 6;
  const int lane = tid & 63;
  const int l15  = lane & 15;
  const int wr   = wave * 32;          // wave's 32 output rows

  f32x4 acc[2][4] = {};

  const int srow = wave * 8 + (lane >> 3);           // 0..31 (row within 32-chunk)
  const int scol = ((lane & 7) ^ (lane >> 3)) * 8;   // pre-swizzled global slot

  for (int kt = 0; kt < K; kt += BK) {
#pragma unroll
    for (int it = 0; it < 4; ++it) {         // A: 128 rows
      const u16* gA = A + (size_t)(row0 + it * 32 + srow) * K + kt + scol;
      u16* lA = &As[(it * 32 + wave * 8) * BK];
      __builtin_amdgcn_global_load_lds((const __attribute__((address_space(1))) void*)gA,
                                       (__attribute__((address_space(3))) void*)lA, 16, 0, 0);
    }
#pragma unroll
    for (int it = 0; it < 2; ++it) {         // B: 64 rows
      const u16* gB = B + (size_t)(col0 + it * 32 + srow) * K + kt + scol;
      u16* lB = &Bs[(it * 32 + wave * 8) * BK];
      __builtin_amdgcn_global_load_lds((const __attribute__((address_space(1))) void*)gB,
                                       (__attribute__((address_space(3))) void*)lB, 16, 0, 0);
    }
    __syncthreads();                         // implicit vmcnt(0) drain + barrier
#pragma unroll
    for (int kk = 0; kk < 2; ++kk) {
      const int kk4 = kk * 4 + (lane >> 4);  // 16B slot index of ko
      const int cs  = (kk4 ^ (l15 & 7)) << 3;  // un-swizzled read column
      s16x8 af[2], bg[4];
#pragma unroll
      for (int mi = 0; mi < 2; ++mi)
        af[mi] = *(const s16x8*)&As[(wr + mi * 16 + l15) * BK + cs];
#pragma unroll
      for (int ni = 0; ni < 4; ++ni)
        bg[ni] = *(const s16x8*)&Bs[(ni * 16 + l15) * BK + cs];
#pragma unroll
      for (int mi = 0; mi < 2; ++mi)
#pragma unroll
        for (int ni = 0; ni < 4; ++ni)
          acc[mi][ni] = __builtin_amdgcn_mfma_f32_16x16x32_bf16(af[mi], bg[ni], acc[mi][ni], 0, 0, 0);
    }
    __syncthreads();
  }

  const int rq = (lane >> 4) * 4;
  const int cq = l15;

  if (MODE == 3) {
#pragma unroll
    for (int mi = 0; mi < 2; ++mi)
#pragma unroll
      for (int ni = 0; ni < 4; ++ni) {
        const int r = row0 + wr + mi * 16 + rq;
        const int c = col0 + ni * 16 + cq;
#pragma unroll
        for (int t = 0; t < 4; ++t)
          ((float*)Cv)[(size_t)(r + t) * N + c] = acc[mi][ni][t];
      }
  } else if (MODE == 2) {
#pragma unroll
    for (int mi = 0; mi < 2; ++mi)
#pragma unroll
      for (int ni = 0; ni < 4; ++ni) {
        const int r = row0 + wr + mi * 16 + rq;
        const int c = col0 + ni * 16 + cq;
        ushort4 o4;
        o4.x = f2bf(acc[mi][ni][0]); o4.y = f2bf(acc[mi][ni][1]);
        o4.z = f2bf(acc[mi][ni][2]); o4.w = f2bf(acc[mi][ni][3]);
        *(ushort4*)&((u16*)Cv)[(size_t)c * S_LEN + r] = o4;
      }
  } else {
    // MODE 0/1: fused rope. col0 is head-aligned (64): d = ni*16+cq (<32) pairs
    // with d+32 = cols of (mi, ni+2) -> rotate-half pair is thread-local.
    // Fast __sinf/__cosf: reduction err ~2e-4 rad at pos<=2047, << bf16 round.
#pragma unroll
    for (int mi = 0; mi < 2; ++mi) {
#pragma unroll
      for (int t = 0; t < 4; ++t) {
        const int i = row0 + wr + mi * 16 + rq + t;
        const float fpos = (float)pos[i];
#pragma unroll
        for (int ni = 0; ni < 2; ++ni) {
          const int d = ni * 16 + cq;            // 0..31
          const int c = col0 + d;
          const float f = exp2f(-(float)(2 * d) * (1.0f / HD) * L2_1E4);
          const float x1 = acc[mi][ni][t], x2 = acc[mi][ni + 2][t];
          if (MODE == 0) {
            const float scl = (i < CTX) ? 1.0f : 0.25f;
            const float a  = fpos * scl * f;
            const float cs = __cosf(a), sn = __sinf(a);
            u16* Cq = (u16*)Cv;
            Cq[(size_t)i * N + c]      = f2bf((x1 * cs - x2 * sn) * QSCL);
            Cq[(size_t)i * N + c + 32] = f2bf((x2 * cs + x1 * sn) * QSCL);
          } else {
            const float ab = fpos * f, an = fpos * 0.25f * f;
            const float cb_ = __cosf(ab), sb_ = __sinf(ab);
            const float cn_ = __cosf(an), sn_ = __sinf(an);
            ((u16*)Cv)[(size_t)i * N + c]       = f2bf(x1 * cb_ - x2 * sb_);
            ((u16*)Cv)[(size_t)i * N + c + 32]  = f2bf(x2 * cb_ + x1 * sb_);
            ((u16*)Cv2)[(size_t)i * N + c]      = f2bf(x1 * cn_ - x2 * sn_);
            ((u16*)Cv2)[(size_t)i * N + c + 32] = f2bf(x2 * cn_ + x1 * sn_);
          }
        }
      }
    }
  }
}

__global__ __launch_bounds__(256) void gemm_qkv(
    const u16* __restrict__ A, const u16* __restrict__ Wq, const u16* __restrict__ Wk,
    const u16* __restrict__ Wv, u16* __restrict__ Q, u16* __restrict__ Kb,
    u16* __restrict__ Kn, u16* __restrict__ Vt, const int* __restrict__ pos)
{
  __shared__ u16 As[BM * BK];
  __shared__ u16 Bs[BN * BK];
  const int bn = blockIdx.x;
  const int row0 = blockIdx.y * BM;
  if (bn < 32)
    gemm_body<0>(As, Bs, A, Wq, Q, nullptr, HIDN, HIDN, row0, bn * BN, pos);
  else if (bn < 40)
    gemm_body<1>(As, Bs, A, Wk, Kb, Kn, KVW, HIDN, row0, (bn - 32) * BN, pos);
  else
    gemm_body<2>(As, Bs, A, Wv, Vt, nullptr, KVW, HIDN, row0, (bn - 40) * BN, pos);
}

__global__ __launch_bounds__(256) void gemm_out(
    const u16* __restrict__ A, const u16* __restrict__ B, float* __restrict__ C, int N, int K)
{
  __shared__ u16 As[BM * BK];
  __shared__ u16 Bs[BN * BK];
  gemm_body<3>(As, Bs, A, B, C, nullptr, N, K, blockIdx.y * BM, blockIdx.x * BN, 0);
}

// ---------------------------------------------------------------------------
// MFMA flash attention — round-2 structure verbatim (best measured, 62.4us):
//  - grid 16 x NH, 256 threads; block p runs q-tile pair {31-p, p} -> exactly
//    33 key-tile iters per block (perfect balance). 4 waves = 2x2 over
//    (row-half x key-half), 32x32 swapped QK^T = mfma(K,Q), lane-local
//    softmax, P->A-frag via cvt_pk+permlane, single-buffer 2-barrier loop
//    with 1-tile register prefetch; cross-wave (O,l) merge per phase.
//  - Rounds 5-9 established: dbuf/barrier-halving +-0, gather-direct 1.9x
//    WORSE, 4 blocks/CU imbalanced worse, 8-wave balanced worse (barrier-
//    locked waves don't hide each other's latency). This is the floor of
//    this structure; keep it.
// ---------------------------------------------------------------------------
#define PAD 8
__global__ __launch_bounds__(256) void attn_mfma(
    const u16* __restrict__ Q, const u16* __restrict__ K, const u16* __restrict__ Kn,
    const u16* __restrict__ Vt, u16* __restrict__ O)
{
  __shared__ __align__(16) u16 Ks[64][HD + PAD];
  __shared__ __align__(16) u16 Kns[64][HD + PAD];
  __shared__ __align__(16) u16 Vts[HD][64 + PAD];
  __shared__ __align__(16) float Of[64][64];   // cross-wave O merge
  __shared__ float Lf[2][32];                  // cross-wave lsum merge
  __shared__ float Li[2][32];                  // per-row 1/l broadcast

  const int tid  = threadIdx.x;
  const int wave = tid >> 6;
  const int lane = tid & 63;
  const int l31  = lane & 31;
  const int hi   = lane >> 5;
  const int wr   = wave >> 1;                  // row half (0,1)
  const int wk   = wave & 1;                   // key half (0,1)
  const int h    = blockIdx.y;
  const int kh   = h >> 2;
  const int pr   = blockIdx.x;                 // pair index 0..15

  // staging map: 2 iters x 256 threads x 16B cover one 64x64 bf16 tile
  int sa[2], sb[2];
#pragma unroll
  for (int it = 0; it < 2; ++it) {
    const int u = it * 256 + tid;
    sa[it] = u >> 3;
    sb[it] = (u & 7) * 8;
  }

  for (int ph = 0; ph < 2; ++ph) {
    const int qt = ph ? pr : 31 - pr;          // heavy tile first
    const int i_base = qt * 64;
    const int rw0 = i_base + wr * 32;          // this wave's 32 q-rows
    const bool mixed_blk = (qt == 31);
    const bool mixed_wv  = mixed_blk && (rw0 + 31 >= CTX);

    // persistent Q B-frags: B[n=q=l31][k=d = i*16 + hi*8 + j]
    s16x8 bq[4];
#pragma unroll
    for (int i = 0; i < 4; ++i)
      bq[i] = *(const s16x8*)(Q + (size_t)(rw0 + l31) * HIDN + h * HD + i * 16 + hi * 8);

    f32x16 acc0 = {};      // O[q][d], d = l31       (rows in reg pattern)
    f32x16 acc1 = {};      // O[q][d], d = l31 + 32
    float lsum = 0.f;      // partial row sum (this lane's 16 keys)

    const int ntiles = qt + 1;
    s16x8 kr[2], vr[2], knr[2];
#pragma unroll
    for (int it = 0; it < 2; ++it) {
      kr[it] = *(const s16x8*)(K  + (size_t)sa[it] * KVW + kh * HD + sb[it]);
      vr[it] = *(const s16x8*)(Vt + (size_t)(kh * HD + sa[it]) * S_LEN + sb[it]);
      if (mixed_blk) knr[it] = *(const s16x8*)(Kn + (size_t)sa[it] * KVW + kh * HD + sb[it]);
    }

    for (int t = 0; t < ntiles; ++t) {
      const int jt = t * 64;
      __syncthreads();                        // LDS free (prev tile's reads done)
#pragma unroll
      for (int it = 0; it < 2; ++it) {
        *(s16x8*)&Ks[sa[it]][sb[it]]  = kr[it];
        *(s16x8*)&Vts[sa[it]][sb[it]] = vr[it];
        if (mixed_blk) *(s16x8*)&Kns[sa[it]][sb[it]] = knr[it];
      }
      __syncthreads();                        // LDS ready
      if (t + 1 < ntiles) {                   // prefetch next tile (overlaps compute)
        const int jn = jt + 64;
#pragma unroll
        for (int it = 0; it < 2; ++it) {
          kr[it] = *(const s16x8*)(K  + (size_t)(jn + sa[it]) * KVW + kh * HD + sb[it]);
          vr[it] = *(const s16x8*)(Vt + (size_t)(kh * HD + sa[it]) * S_LEN + jn + sb[it]);
          if (mixed_blk) knr[it] = *(const s16x8*)(Kn + (size_t)(jn + sa[it]) * KVW + kh * HD + sb[it]);
        }
      }

      const int j0 = jt + wk * 32;            // this wave's 32-key group
      if (j0 > rw0 + 31) continue;            // fully masked for this wave
      const bool needmask = (j0 + 31 > rw0);  // straddles the diagonal

      // swapped QK^T: D[m=key (reg pattern)][n=q (l31)]
      f32x16 sc = {};
#pragma unroll
      for (int i = 0; i < 4; ++i) {
        const s16x8 ak = *(const s16x8*)&Ks[wk * 32 + l31][i * 16 + hi * 8];
        sc = __builtin_amdgcn_mfma_f32_32x32x16_bf16(ak, bq[i], sc, 0, 0, 0);
      }
      if (mixed_wv) {                         // rows straddle CTX: also narrow scores
        f32x16 scn = {};
#pragma unroll
        for (int i = 0; i < 4; ++i) {
          const s16x8 ak = *(const s16x8*)&Kns[wk * 32 + l31][i * 16 + hi * 8];
          scn = __builtin_amdgcn_mfma_f32_32x32x16_bf16(ak, bq[i], scn, 0, 0, 0);
        }
        const bool nar = (rw0 + l31) >= CTX;  // per-lane: q-row selects rope
#pragma unroll
        for (int r = 0; r < 16; ++r) sc[r] = nar ? scn[r] : sc[r];
      }

      // lane-local softmax: p = exp2(min(s,80)) (Q pre-scaled by log2e/8)
      float p[16];
#pragma unroll
      for (int r = 0; r < 16; ++r) {
        float e = __builtin_amdgcn_exp2f(fminf(sc[r], 80.f));
        if (needmask) {
          const int key = j0 + (r & 3) + 8 * (r >> 2) + 4 * hi;
          e = (key > rw0 + l31) ? 0.f : e;
        }
        p[r] = e;
        lsum += e;
      }

      // pack p -> bf16 pairs: c[blk][j] = keys 8*blk + 4*hi + {2j, 2j+1}
      unsigned int c[4][2];
#pragma unroll
      for (int blk = 0; blk < 4; ++blk) {
        c[blk][0] = cvt_pk_bf16(p[4 * blk + 0], p[4 * blk + 1]);
        c[blk][1] = cvt_pk_bf16(p[4 * blk + 2], p[4 * blk + 3]);
      }

      // per 16-key slice s: swap halves -> A-frag words, then 2 PV MFMAs
#pragma unroll
      for (int s = 0; s < 2; ++s) {
        unsigned int w0 = c[2 * s][0], w2 = c[2 * s + 1][0];
        unsigned int w1 = c[2 * s][1], w3 = c[2 * s + 1][1];
        asm("v_permlane32_swap_b32 %0, %1" : "+v"(w0), "+v"(w2));
        asm("v_permlane32_swap_b32 %0, %1" : "+v"(w1), "+v"(w3));
        union { unsigned int u[4]; s16x8 v; } af;
        af.u[0] = w0; af.u[1] = w1; af.u[2] = w2; af.u[3] = w3;
        const int kc = wk * 32 + s * 16 + hi * 8;
        const s16x8 v0 = *(const s16x8*)&Vts[l31][kc];
        const s16x8 v1 = *(const s16x8*)&Vts[32 + l31][kc];
        acc0 = __builtin_amdgcn_mfma_f32_32x32x16_bf16(af.v, v0, acc0, 0, 0, 0);
        acc1 = __builtin_amdgcn_mfma_f32_32x32x16_bf16(af.v, v1, acc1, 0, 0, 0);
      }
    }

    // ---- cross-wave merge over key halves + epilogue (per phase) ----
    lsum += __shfl_xor(lsum, 32, 64);         // combine hi halves: row sum over
                                              // this wave's 32 keys, row = rw0+l31
    __syncthreads();                          // all compute done; LDS tiles free
    if (wk == 1) {
#pragma unroll
      for (int r = 0; r < 16; ++r) {
        const int rl = (r & 3) + 8 * (r >> 2) + 4 * hi;
        Of[wr * 32 + rl][l31]      = acc0[r];
        Of[wr * 32 + rl][l31 + 32] = acc1[r];
      }
      if (hi == 0) Lf[wr][l31] = lsum;
    }
    __syncthreads();
    if (wk == 0) {
      const float tot = lsum + Lf[wr][l31];
      const float inv = 1.0f / fmaxf(tot, 1e-30f);
      if (hi == 0) Li[wr][l31] = inv;         // same-wave write->read (in-order LDS)
#pragma unroll
      for (int r = 0; r < 16; ++r) {
        const int rl = (r & 3) + 8 * (r >> 2) + 4 * hi;
        const float iv = Li[wr][rl];
        const size_t o = (size_t)(rw0 + rl) * HIDN + h * HD + l31;
        O[o]      = f2bf((acc0[r] + Of[wr * 32 + rl][l31])      * iv);
        O[o + 32] = f2bf((acc1[r] + Of[wr * 32 + rl][l31 + 32]) * iv);
      }
    }
  }
}

// ---------------------------------------------------------------------------
extern "C" void kernel_launch(void* const* d_in, const int* in_sizes, int n_in,
                              void* d_out, int out_size, void* d_ws, size_t ws_size,
                              hipStream_t stream)
{
  const float* hidden = (const float*)d_in[0];
  const int* pos      = (const int*)d_in[2];   // d_in[1] mask: pure causal, unused
  const float* Wq = (const float*)d_in[3];
  const float* Wk = (const float*)d_in[4];
  const float* Wv = (const float*)d_in[5];
  const float* Wo = (const float*)d_in[6];
  float* out = (float*)d_out;

  char* ws = (char*)d_ws;
  u16* Qb  = (u16*)(ws);                    // 8 MB  bf16 Q (roped+scaled by gemm)
  u16* Kbb = (u16*)(ws + (8u  << 20));      // 2 MB  bf16 boost K (roped by gemm)
  u16* Knb = (u16*)(ws + (10u << 20));      // 2 MB  bf16 narrow K
  u16* Vtb = (u16*)(ws + (12u << 20));      // 2 MB  bf16 V transposed [kv_col][seq]
  u16* Ab  = (u16*)(ws + (14u << 20));      // 8 MB  bf16 attention output
  u16* Hb  = (u16*)(ws + (22u << 20));      // 8 MB  bf16 hidden
  u16* Wqb = (u16*)(ws + (30u << 20));      // 8 MB  bf16 Wq
  u16* Wkb = (u16*)(ws + (38u << 20));      // 2 MB  bf16 Wk
  u16* Wvb = (u16*)(ws + (40u << 20));      // 2 MB  bf16 Wv
  u16* Wob = (u16*)(ws + (42u << 20));      // 8 MB  bf16 Wo  => 50 MB total

  conv_all<<<dim3(14336), 256, 0, stream>>>(hidden, Wq, Wk, Wv, Wo, Hb, Wqb, Wkb, Wvb, Wob);
  gemm_qkv<<<dim3(48, 16), 256, 0, stream>>>(Hb, Wqb, Wkb, Wvb, Qb, Kbb, Knb, Vtb, pos);
  attn_mfma<<<dim3(16, NH), 256, 0, stream>>>(Qb, Kbb, Knb, Vtb, Ab);
  gemm_out<<<dim3(32, 16), 256, 0, stream>>>(Ab, Wob, out, HIDN, HIDN);
}

// Round 11
// 231.234 us; speedup vs baseline: 1.3128x; 1.0104x over previous
//
#include <hip/hip_runtime.h>
#include <math.h>

#define S_LEN 2048
#define HIDN  2048
#define NH    32
#define NKV   8
#define HD    64
#define KVW   (NKV * HD)     // 512
#define CTX   (S_LEN - 10)   // 2038: rows < CTX use boost rope, rows >= CTX use narrow

typedef unsigned short u16;
typedef __attribute__((ext_vector_type(4))) float f32x4;
typedef __attribute__((ext_vector_type(16))) float f32x16;
typedef __attribute__((ext_vector_type(8))) short s16x8;

#define QSCL 0.18033688011112042f    // 0.125 * log2(e): attn uses exp2(score)
#define L2_1E4 13.287712379549449f   // log2(10000)

__device__ __forceinline__ float bf2f(u16 u) {
  union { unsigned int i; float f; } v; v.i = ((unsigned int)u) << 16; return v.f;
}
__device__ __forceinline__ u16 f2bf(float f) {
  union { float f; unsigned int i; } v; v.f = f;
  unsigned int r = v.i + 0x7fffu + ((v.i >> 16) & 1u);
  return (u16)(r >> 16);
}
__device__ __forceinline__ unsigned int cvt_pk_bf16(float a, float b) {
  unsigned int d;
  asm("v_cvt_pk_bf16_f32 %0, %1, %2" : "=v"(d) : "v"(a), "v"(b));
  return d;
}

// ---------------------------------------------------------------------------
// fp32 -> bf16 conversion: hidden + Wq + Wk + Wv + Wo in one launch.
// ---------------------------------------------------------------------------
__global__ __launch_bounds__(256) void conv_all(
    const float* __restrict__ h,  const float* __restrict__ wq,
    const float* __restrict__ wk, const float* __restrict__ wv,
    const float* __restrict__ wo,
    u16* __restrict__ Hb, u16* __restrict__ Wqb, u16* __restrict__ Wkb,
    u16* __restrict__ Wvb, u16* __restrict__ Wob)
{
  const int i = blockIdx.x * 256 + threadIdx.x;   // one float4 per thread
  const float* src; u16* dst; int off;
  if      (i < 1048576) { src = h;  dst = Hb;  off = i; }
  else if (i < 2097152) { src = wq; dst = Wqb; off = i - 1048576; }
  else if (i < 2359296) { src = wk; dst = Wkb; off = i - 2097152; }
  else if (i < 2621440) { src = wv; dst = Wvb; off = i - 2359296; }
  else                  { src = wo; dst = Wob; off = i - 2621440; }
  const float4 f4 = ((const float4*)src)[off];
  ushort4 o4;
  o4.x = f2bf(f4.x); o4.y = f2bf(f4.y); o4.z = f2bf(f4.z); o4.w = f2bf(f4.w);
  ((ushort4*)dst)[off] = o4;
}

// ---------------------------------------------------------------------------
// GEMM: C[M,N] = A[M,K] * B[N,K]^T (bf16 in, fp32 accum), 128x64 tile.
// NEW: BK=128 — halves barrier/drain events (16 K-steps vs 32) while LDS
// stays 48KB -> 3 blocks/CU retained (m132's BK=128 regression was the
// 64KB/occupancy case; this tile avoids it). T2 XOR swizzle adapted to
// 16 slots/row: LDS slot s of row r holds global slot s^(r&7); reads
// use slot (kk*4+quad)^(l15&7) -> 2 lanes/slot, conflict-free.
// MODE: 0 = Q (fused rope boost/narrow + QSCL, bf16)
//       1 = K (fused rope dual: boost -> Cv, narrow -> Cv2, bf16)
//       2 = V (write C^T, row stride S_LEN, bf16)
//       3 = OUT (f32)
// ---------------------------------------------------------------------------
#define BM 128
#define BN 64
#define BK 128

template<int MODE>
__device__ __forceinline__ void gemm_body(
    u16* __restrict__ As, u16* __restrict__ Bs,
    const u16* __restrict__ A, const u16* __restrict__ B,
    void* __restrict__ Cv, void* __restrict__ Cv2,
    int N, int K, int row0, int col0, const int* __restrict__ pos)
{
  const int tid  = threadIdx.x;
  const int wave = tid >> 6;
  const int lane = tid & 63;
  const int l15  = lane & 15;
  const int wr   = wave * 32;          // wave's 32 output rows

  f32x4 acc[2][4] = {};

  const int sr    = lane >> 4;         // 0..3: row within 4-row wave chunk
  const int sslot = lane & 15;         // 16B slot within row

  for (int kt = 0; kt < K; kt += BK) {
#pragma unroll
    for (int it = 0; it < 8; ++it) {         // A: 128 rows x 128 cols
      const int rb = it * 16 + wave * 4;
      const int r  = rb + sr;
      const u16* gA = A + (size_t)(row0 + r) * K + kt + ((sslot ^ (r & 7)) << 3);
      u16* lA = &As[rb * BK];
      __builtin_amdgcn_global_load_lds((const __attribute__((address_space(1))) void*)gA,
                                       (__attribute__((address_space(3))) void*)lA, 16, 0, 0);
    }
#pragma unroll
    for (int it = 0; it < 4; ++it) {         // B: 64 rows x 128 cols
      const int rb = it * 16 + wave * 4;
      const int r  = rb + sr;
      const u16* gB = B + (size_t)(col0 + r) * K + kt + ((sslot ^ (r & 7)) << 3);
      u16* lB = &Bs[rb * BK];
      __builtin_amdgcn_global_load_lds((const __attribute__((address_space(1))) void*)gB,
                                       (__attribute__((address_space(3))) void*)lB, 16, 0, 0);
    }
    __syncthreads();                         // implicit vmcnt(0) drain + barrier
#pragma unroll
    for (int kk = 0; kk < 4; ++kk) {
      const int cs = ((kk * 4 + sr) ^ (l15 & 7)) << 3;   // un-swizzled read col
      s16x8 af[2], bg[4];
#pragma unroll
      for (int mi = 0; mi < 2; ++mi)
        af[mi] = *(const s16x8*)&As[(wr + mi * 16 + l15) * BK + cs];
#pragma unroll
      for (int ni = 0; ni < 4; ++ni)
        bg[ni] = *(const s16x8*)&Bs[(ni * 16 + l15) * BK + cs];
#pragma unroll
      for (int mi = 0; mi < 2; ++mi)
#pragma unroll
        for (int ni = 0; ni < 4; ++ni)
          acc[mi][ni] = __builtin_amdgcn_mfma_f32_16x16x32_bf16(af[mi], bg[ni], acc[mi][ni], 0, 0, 0);
    }
    __syncthreads();
  }

  const int rq = (lane >> 4) * 4;
  const int cq = l15;

  if (MODE == 3) {
#pragma unroll
    for (int mi = 0; mi < 2; ++mi)
#pragma unroll
      for (int ni = 0; ni < 4; ++ni) {
        const int r = row0 + wr + mi * 16 + rq;
        const int c = col0 + ni * 16 + cq;
#pragma unroll
        for (int t = 0; t < 4; ++t)
          ((float*)Cv)[(size_t)(r + t) * N + c] = acc[mi][ni][t];
      }
  } else if (MODE == 2) {
#pragma unroll
    for (int mi = 0; mi < 2; ++mi)
#pragma unroll
      for (int ni = 0; ni < 4; ++ni) {
        const int r = row0 + wr + mi * 16 + rq;
        const int c = col0 + ni * 16 + cq;
        ushort4 o4;
        o4.x = f2bf(acc[mi][ni][0]); o4.y = f2bf(acc[mi][ni][1]);
        o4.z = f2bf(acc[mi][ni][2]); o4.w = f2bf(acc[mi][ni][3]);
        *(ushort4*)&((u16*)Cv)[(size_t)c * S_LEN + r] = o4;
      }
  } else {
    // MODE 0/1: fused rope. col0 is head-aligned (64): d = ni*16+cq (<32) pairs
    // with d+32 = cols of (mi, ni+2) -> rotate-half pair is thread-local.
    // Fast __sinf/__cosf: reduction err ~2e-4 rad at pos<=2047, << bf16 round.
#pragma unroll
    for (int mi = 0; mi < 2; ++mi) {
#pragma unroll
      for (int t = 0; t < 4; ++t) {
        const int i = row0 + wr + mi * 16 + rq + t;
        const float fpos = (float)pos[i];
#pragma unroll
        for (int ni = 0; ni < 2; ++ni) {
          const int d = ni * 16 + cq;            // 0..31
          const int c = col0 + d;
          const float f = exp2f(-(float)(2 * d) * (1.0f / HD) * L2_1E4);
          const float x1 = acc[mi][ni][t], x2 = acc[mi][ni + 2][t];
          if (MODE == 0) {
            const float scl = (i < CTX) ? 1.0f : 0.25f;
            const float a  = fpos * scl * f;
            const float cs = __cosf(a), sn = __sinf(a);
            u16* Cq = (u16*)Cv;
            Cq[(size_t)i * N + c]      = f2bf((x1 * cs - x2 * sn) * QSCL);
            Cq[(size_t)i * N + c + 32] = f2bf((x2 * cs + x1 * sn) * QSCL);
          } else {
            const float ab = fpos * f, an = fpos * 0.25f * f;
            const float cb_ = __cosf(ab), sb_ = __sinf(ab);
            const float cn_ = __cosf(an), sn_ = __sinf(an);
            ((u16*)Cv)[(size_t)i * N + c]       = f2bf(x1 * cb_ - x2 * sb_);
            ((u16*)Cv)[(size_t)i * N + c + 32]  = f2bf(x2 * cb_ + x1 * sb_);
            ((u16*)Cv2)[(size_t)i * N + c]      = f2bf(x1 * cn_ - x2 * sn_);
            ((u16*)Cv2)[(size_t)i * N + c + 32] = f2bf(x2 * cn_ + x1 * sn_);
          }
        }
      }
    }
  }
}

__global__ __launch_bounds__(256) void gemm_qkv(
    const u16* __restrict__ A, const u16* __restrict__ Wq, const u16* __restrict__ Wk,
    const u16* __restrict__ Wv, u16* __restrict__ Q, u16* __restrict__ Kb,
    u16* __restrict__ Kn, u16* __restrict__ Vt, const int* __restrict__ pos)
{
  __shared__ u16 As[BM * BK];
  __shared__ u16 Bs[BN * BK];
  const int bn = blockIdx.x;
  const int row0 = blockIdx.y * BM;
  if (bn < 32)
    gemm_body<0>(As, Bs, A, Wq, Q, nullptr, HIDN, HIDN, row0, bn * BN, pos);
  else if (bn < 40)
    gemm_body<1>(As, Bs, A, Wk, Kb, Kn, KVW, HIDN, row0, (bn - 32) * BN, pos);
  else
    gemm_body<2>(As, Bs, A, Wv, Vt, nullptr, KVW, HIDN, row0, (bn - 40) * BN, pos);
}

__global__ __launch_bounds__(256) void gemm_out(
    const u16* __restrict__ A, const u16* __restrict__ B, float* __restrict__ C, int N, int K)
{
  __shared__ u16 As[BM * BK];
  __shared__ u16 Bs[BN * BK];
  gemm_body<3>(As, Bs, A, B, C, nullptr, N, K, blockIdx.y * BM, blockIdx.x * BN, 0);
}

// ---------------------------------------------------------------------------
// MFMA flash attention — round-2 structure verbatim (best measured, 62.0us):
//  - grid 16 x NH, 256 threads; block p runs q-tile pair {31-p, p} -> exactly
//    33 key-tile iters per block (perfect balance). 4 waves = 2x2 over
//    (row-half x key-half), 32x32 swapped QK^T = mfma(K,Q), lane-local
//    softmax, P->A-frag via cvt_pk+permlane, single-buffer 2-barrier loop
//    with 1-tile register prefetch; cross-wave (O,l) merge per phase.
//  - Rounds 5-9 established: dbuf/barrier-halving +-0, gather-direct 1.9x
//    WORSE, 4 blocks/CU imbalanced worse, 8-wave balanced worse (barrier-
//    locked waves don't hide each other's latency). This is the floor of
//    this structure; keep it.
// ---------------------------------------------------------------------------
#define PAD 8
__global__ __launch_bounds__(256) void attn_mfma(
    const u16* __restrict__ Q, const u16* __restrict__ K, const u16* __restrict__ Kn,
    const u16* __restrict__ Vt, u16* __restrict__ O)
{
  __shared__ __align__(16) u16 Ks[64][HD + PAD];
  __shared__ __align__(16) u16 Kns[64][HD + PAD];
  __shared__ __align__(16) u16 Vts[HD][64 + PAD];
  __shared__ __align__(16) float Of[64][64];   // cross-wave O merge
  __shared__ float Lf[2][32];                  // cross-wave lsum merge
  __shared__ float Li[2][32];                  // per-row 1/l broadcast

  const int tid  = threadIdx.x;
  const int wave = tid >> 6;
  const int lane = tid & 63;
  const int l31  = lane & 31;
  const int hi   = lane >> 5;
  const int wr   = wave >> 1;                  // row half (0,1)
  const int wk   = wave & 1;                   // key half (0,1)
  const int h    = blockIdx.y;
  const int kh   = h >> 2;
  const int pr   = blockIdx.x;                 // pair index 0..15

  // staging map: 2 iters x 256 threads x 16B cover one 64x64 bf16 tile
  int sa[2], sb[2];
#pragma unroll
  for (int it = 0; it < 2; ++it) {
    const int u = it * 256 + tid;
    sa[it] = u >> 3;
    sb[it] = (u & 7) * 8;
  }

  for (int ph = 0; ph < 2; ++ph) {
    const int qt = ph ? pr : 31 - pr;          // heavy tile first
    const int i_base = qt * 64;
    const int rw0 = i_base + wr * 32;          // this wave's 32 q-rows
    const bool mixed_blk = (qt == 31);
    const bool mixed_wv  = mixed_blk && (rw0 + 31 >= CTX);

    // persistent Q B-frags: B[n=q=l31][k=d = i*16 + hi*8 + j]
    s16x8 bq[4];
#pragma unroll
    for (int i = 0; i < 4; ++i)
      bq[i] = *(const s16x8*)(Q + (size_t)(rw0 + l31) * HIDN + h * HD + i * 16 + hi * 8);

    f32x16 acc0 = {};      // O[q][d], d = l31       (rows in reg pattern)
    f32x16 acc1 = {};      // O[q][d], d = l31 + 32
    float lsum = 0.f;      // partial row sum (this lane's 16 keys)

    const int ntiles = qt + 1;
    s16x8 kr[2], vr[2], knr[2];
#pragma unroll
    for (int it = 0; it < 2; ++it) {
      kr[it] = *(const s16x8*)(K  + (size_t)sa[it] * KVW + kh * HD + sb[it]);
      vr[it] = *(const s16x8*)(Vt + (size_t)(kh * HD + sa[it]) * S_LEN + sb[it]);
      if (mixed_blk) knr[it] = *(const s16x8*)(Kn + (size_t)sa[it] * KVW + kh * HD + sb[it]);
    }

    for (int t = 0; t < ntiles; ++t) {
      const int jt = t * 64;
      __syncthreads();                        // LDS free (prev tile's reads done)
#pragma unroll
      for (int it = 0; it < 2; ++it) {
        *(s16x8*)&Ks[sa[it]][sb[it]]  = kr[it];
        *(s16x8*)&Vts[sa[it]][sb[it]] = vr[it];
        if (mixed_blk) *(s16x8*)&Kns[sa[it]][sb[it]] = knr[it];
      }
      __syncthreads();                        // LDS ready
      if (t + 1 < ntiles) {                   // prefetch next tile (overlaps compute)
        const int jn = jt + 64;
#pragma unroll
        for (int it = 0; it < 2; ++it) {
          kr[it] = *(const s16x8*)(K  + (size_t)(jn + sa[it]) * KVW + kh * HD + sb[it]);
          vr[it] = *(const s16x8*)(Vt + (size_t)(kh * HD + sa[it]) * S_LEN + jn + sb[it]);
          if (mixed_blk) knr[it] = *(const s16x8*)(Kn + (size_t)(jn + sa[it]) * KVW + kh * HD + sb[it]);
        }
      }

      const int j0 = jt + wk * 32;            // this wave's 32-key group
      if (j0 > rw0 + 31) continue;            // fully masked for this wave
      const bool needmask = (j0 + 31 > rw0);  // straddles the diagonal

      // swapped QK^T: D[m=key (reg pattern)][n=q (l31)]
      f32x16 sc = {};
#pragma unroll
      for (int i = 0; i < 4; ++i) {
        const s16x8 ak = *(const s16x8*)&Ks[wk * 32 + l31][i * 16 + hi * 8];
        sc = __builtin_amdgcn_mfma_f32_32x32x16_bf16(ak, bq[i], sc, 0, 0, 0);
      }
      if (mixed_wv) {                         // rows straddle CTX: also narrow scores
        f32x16 scn = {};
#pragma unroll
        for (int i = 0; i < 4; ++i) {
          const s16x8 ak = *(const s16x8*)&Kns[wk * 32 + l31][i * 16 + hi * 8];
          scn = __builtin_amdgcn_mfma_f32_32x32x16_bf16(ak, bq[i], scn, 0, 0, 0);
        }
        const bool nar = (rw0 + l31) >= CTX;  // per-lane: q-row selects rope
#pragma unroll
        for (int r = 0; r < 16; ++r) sc[r] = nar ? scn[r] : sc[r];
      }

      // lane-local softmax: p = exp2(min(s,80)) (Q pre-scaled by log2e/8)
      float p[16];
#pragma unroll
      for (int r = 0; r < 16; ++r) {
        float e = __builtin_amdgcn_exp2f(fminf(sc[r], 80.f));
        if (needmask) {
          const int key = j0 + (r & 3) + 8 * (r >> 2) + 4 * hi;
          e = (key > rw0 + l31) ? 0.f : e;
        }
        p[r] = e;
        lsum += e;
      }

      // pack p -> bf16 pairs: c[blk][j] = keys 8*blk + 4*hi + {2j, 2j+1}
      unsigned int c[4][2];
#pragma unroll
      for (int blk = 0; blk < 4; ++blk) {
        c[blk][0] = cvt_pk_bf16(p[4 * blk + 0], p[4 * blk + 1]);
        c[blk][1] = cvt_pk_bf16(p[4 * blk + 2], p[4 * blk + 3]);
      }

      // per 16-key slice s: swap halves -> A-frag words, then 2 PV MFMAs
#pragma unroll
      for (int s = 0; s < 2; ++s) {
        unsigned int w0 = c[2 * s][0], w2 = c[2 * s + 1][0];
        unsigned int w1 = c[2 * s][1], w3 = c[2 * s + 1][1];
        asm("v_permlane32_swap_b32 %0, %1" : "+v"(w0), "+v"(w2));
        asm("v_permlane32_swap_b32 %0, %1" : "+v"(w1), "+v"(w3));
        union { unsigned int u[4]; s16x8 v; } af;
        af.u[0] = w0; af.u[1] = w1; af.u[2] = w2; af.u[3] = w3;
        const int kc = wk * 32 + s * 16 + hi * 8;
        const s16x8 v0 = *(const s16x8*)&Vts[l31][kc];
        const s16x8 v1 = *(const s16x8*)&Vts[32 + l31][kc];
        acc0 = __builtin_amdgcn_mfma_f32_32x32x16_bf16(af.v, v0, acc0, 0, 0, 0);
        acc1 = __builtin_amdgcn_mfma_f32_32x32x16_bf16(af.v, v1, acc1, 0, 0, 0);
      }
    }

    // ---- cross-wave merge over key halves + epilogue (per phase) ----
    lsum += __shfl_xor(lsum, 32, 64);         // combine hi halves: row sum over
                                              // this wave's 32 keys, row = rw0+l31
    __syncthreads();                          // all compute done; LDS tiles free
    if (wk == 1) {
#pragma unroll
      for (int r = 0; r < 16; ++r) {
        const int rl = (r & 3) + 8 * (r >> 2) + 4 * hi;
        Of[wr * 32 + rl][l31]      = acc0[r];
        Of[wr * 32 + rl][l31 + 32] = acc1[r];
      }
      if (hi == 0) Lf[wr][l31] = lsum;
    }
    __syncthreads();
    if (wk == 0) {
      const float tot = lsum + Lf[wr][l31];
      const float inv = 1.0f / fmaxf(tot, 1e-30f);
      if (hi == 0) Li[wr][l31] = inv;         // same-wave write->read (in-order LDS)
#pragma unroll
      for (int r = 0; r < 16; ++r) {
        const int rl = (r & 3) + 8 * (r >> 2) + 4 * hi;
        const float iv = Li[wr][rl];
        const size_t o = (size_t)(rw0 + rl) * HIDN + h * HD + l31;
        O[o]      = f2bf((acc0[r] + Of[wr * 32 + rl][l31])      * iv);
        O[o + 32] = f2bf((acc1[r] + Of[wr * 32 + rl][l31 + 32]) * iv);
      }
    }
  }
}

// ---------------------------------------------------------------------------
extern "C" void kernel_launch(void* const* d_in, const int* in_sizes, int n_in,
                              void* d_out, int out_size, void* d_ws, size_t ws_size,
                              hipStream_t stream)
{
  const float* hidden = (const float*)d_in[0];
  const int* pos      = (const int*)d_in[2];   // d_in[1] mask: pure causal, unused
  const float* Wq = (const float*)d_in[3];
  const float* Wk = (const float*)d_in[4];
  const float* Wv = (const float*)d_in[5];
  const float* Wo = (const float*)d_in[6];
  float* out = (float*)d_out;

  char* ws = (char*)d_ws;
  u16* Qb  = (u16*)(ws);                    // 8 MB  bf16 Q (roped+scaled by gemm)
  u16* Kbb = (u16*)(ws + (8u  << 20));      // 2 MB  bf16 boost K (roped by gemm)
  u16* Knb = (u16*)(ws + (10u << 20));      // 2 MB  bf16 narrow K
  u16* Vtb = (u16*)(ws + (12u << 20));      // 2 MB  bf16 V transposed [kv_col][seq]
  u16* Ab  = (u16*)(ws + (14u << 20));      // 8 MB  bf16 attention output
  u16* Hb  = (u16*)(ws + (22u << 20));      // 8 MB  bf16 hidden
  u16* Wqb = (u16*)(ws + (30u << 20));      // 8 MB  bf16 Wq
  u16* Wkb = (u16*)(ws + (38u << 20));      // 2 MB  bf16 Wk
  u16* Wvb = (u16*)(ws + (40u << 20));      // 2 MB  bf16 Wv
  u16* Wob = (u16*)(ws + (42u << 20));      // 8 MB  bf16 Wo  => 50 MB total

  conv_all<<<dim3(14336), 256, 0, stream>>>(hidden, Wq, Wk, Wv, Wo, Hb, Wqb, Wkb, Wvb, Wob);
  gemm_qkv<<<dim3(48, 16), 256, 0, stream>>>(Hb, Wqb, Wkb, Wvb, Qb, Kbb, Knb, Vtb, pos);
  attn_mfma<<<dim3(16, NH), 256, 0, stream>>>(Qb, Kbb, Knb, Vtb, Ab);
  gemm_out<<<dim3(32, 16), 256, 0, stream>>>(Ab, Wob, out, HIDN, HIDN);
}